// Round 6
// baseline (479.866 us; speedup 1.0000x reference)
//
#include <hip/hip_runtime.h>

#define L_SEQ 512
#define BATCH 2
#define NROWS (BATCH*L_SEQ)   // 1024
#define DMODEL 512
#define DINNER 1024
#define DSTATE 128
#define NHEADSM 16
#define CONVD 1280
#define DINPROJ 2320
#define QCH 32
#define NCH 16
#define WI_PAD 2368           // 2320 padded to x64
#define WH_PAD 1024           // 1000 padded to x64

// ws float offsets (after 256B header holding the dtype flag)
#define W_CONVW 0
#define W_CONVB 10240
#define W_DTB   12800
#define W_ALOG  12832
#define W_DD    12864
#define W_RMSW  12896
#define W_LNW   14944
#define W_LNB   15968
#define W_HEADB 16992
#define O_X     18048
#define O_ZX    (O_X  + NROWS*DMODEL)
#define O_XC    (O_ZX + NROWS*DINPROJ)   // reused: CbS bf16 region (4 MB)
#define O_DT    (O_XC + NROWS*CONVD)
#define O_Y     (O_DT + NROWS*NHEADSM)
#define O_O     (O_Y  + NROWS*DINNER)
#define O_LA    (O_O  + NROWS*DMODEL)
#define O_S     (O_LA + 16384)
#define O_UB    (O_S  + 4194304)
// ushort offsets within bf16 region:
#define U_WI   0
#define U_WO   2424832
#define U_WH   3473408
#define U_XBF  3997696
#define U_YBF  4521984

#define NPREPW (2*WI_PAD + 2*DMODEL + WH_PAD)   // 6848 weight rows

typedef __attribute__((ext_vector_type(8))) short short8;
typedef __attribute__((ext_vector_type(4))) float floatx4;

__device__ __forceinline__ float b2f(unsigned short h){ return __uint_as_float(((unsigned)h)<<16); }
__device__ __forceinline__ unsigned short f2b(float x){
  unsigned u = __float_as_uint(x);
  return (unsigned short)((u + 0x7fffu + ((u>>16)&1u)) >> 16);
}
__device__ __forceinline__ float loadIn(const void* p, long i, int f){
  return f ? b2f(((const unsigned short*)p)[i]) : ((const float*)p)[i];
}
__device__ __forceinline__ float silu(float s){ return s / (1.f + __expf(-s)); }

// ---- dtype detect: low-16 of f32 words are a bf16 value iff data is packed bf16 ----
__global__ void k_detect(const unsigned* __restrict__ emb, int* __restrict__ flag){
  __shared__ int red[256];
  int t = threadIdx.x; int cnt = 0;
  for (int i = 0; i < 16; i++){
    unsigned w = emb[t*16 + i];
    unsigned e = (w >> 7) & 0xffu;
    cnt += (e >= 100 && e <= 126) ? 1 : 0;
  }
  red[t] = cnt; __syncthreads();
  if (t == 0){
    int s = 0;
    for (int i = 0; i < 256; i++) s += red[i];
    *flag = (s > 2048) ? 1 : 0;
  }
}

struct ConvArgs { const void* src[9]; int off[10]; };

// fused startup: small-param convert + weight bf16 prep + embedding
__global__ void k_prep(ConvArgs a, const void* __restrict__ wi, const void* __restrict__ wo,
                       const void* __restrict__ wh, const int* __restrict__ tok,
                       const void* __restrict__ emb, const int* __restrict__ flag,
                       float* __restrict__ dstSmall,
                       unsigned short* __restrict__ WiB, unsigned short* __restrict__ WoB,
                       unsigned short* __restrict__ WhB,
                       float* __restrict__ x, unsigned short* __restrict__ xbf)
{
  int f = *flag;
  int blk = blockIdx.x;
  if (blk < 71){
    int i = blk*256 + threadIdx.x;
    if (i < a.off[9]){
      int s = 0;
      while (i >= a.off[s+1]) s++;
      dstSmall[i] = loadIn(a.src[s], i - a.off[s], f);
    }
    return;
  }
  blk -= 71;
  if (blk < NPREPW){
    int r = blk;
    const void* src = nullptr; unsigned short* dst; long sb = 0, db; int K; bool zero = false;
    if (r < 2*WI_PAD){
      int layer = r / WI_PAD, row = r % WI_PAD;
      K = DMODEL; dst = WiB; db = ((long)layer*WI_PAD + row)*DMODEL;
      if (row < DINPROJ){ src = wi; sb = ((long)layer*DINPROJ + row)*DMODEL; } else zero = true;
    } else if (r < 2*WI_PAD + 2*DMODEL){
      int rr = r - 2*WI_PAD;
      K = DINNER; dst = WoB; db = (long)rr*DINNER;
      src = wo; sb = db;
    } else {
      int row = r - 2*WI_PAD - 2*DMODEL;
      K = DMODEL; dst = WhB; db = (long)row*DMODEL;
      if (row < 1000){ src = wh; sb = db; } else zero = true;
    }
    for (int c = threadIdx.x; c < K; c += 256)
      dst[db + c] = zero ? (unsigned short)0
                         : (f ? ((const unsigned short*)src)[sb + c] : f2b(((const float*)src)[sb + c]));
    return;
  }
  int r = blk - NPREPW;   // embed row
  long base = (long)tok[r] * DMODEL;
  for (int c = threadIdx.x; c < DMODEL; c += 256){
    float v = loadIn(emb, base + c, f);
    x[(long)r*DMODEL + c] = v;
    xbf[(long)r*DMODEL + c] = f ? ((const unsigned short*)emb)[base + c] : f2b(v);
  }
}

// ======== bf16 MFMA GEMM: C[M,N] = A[M,K] @ B[N,K]^T (+bias) ========
__global__ __launch_bounds__(256) void k_mfma_nt(
    const unsigned short* __restrict__ A, const unsigned short* __restrict__ B,
    void* __restrict__ C, int M, int N, int K,
    const float* __restrict__ bias, const int* __restrict__ flag, int outDual)
{
  __shared__ unsigned short As[4096];
  __shared__ unsigned short Bs[4096];
  int f = *flag;
  int t = threadIdx.x;
  int w = t >> 6, lane = t & 63;
  int quad = lane >> 4, l16 = lane & 15;
  int m0 = blockIdx.y << 6, n0 = blockIdx.x << 6;
  int wm = (w & 1) << 5, wn = (w >> 1) << 5;
  floatx4 acc[2][2];
  #pragma unroll
  for (int mi = 0; mi < 2; mi++)
    #pragma unroll
    for (int ni = 0; ni < 2; ni++) acc[mi][ni] = (floatx4){0.f,0.f,0.f,0.f};

  int idx0 = (w << 7) + lane;
  int r0s = idx0 >> 3, g0 = idx0 & 7;
  int idx1 = idx0 + 64;
  int r1s = idx1 >> 3, g1 = idx1 & 7;
  long aOff0 = (long)(m0 + r0s)*K + g0*8;
  long aOff1 = (long)(m0 + r1s)*K + g1*8;
  long bOff0 = (long)(n0 + r0s)*K + g0*8;
  long bOff1 = (long)(n0 + r1s)*K + g1*8;
  int w0 = r0s*64 + (g0 ^ (r0s & 7))*8;
  int w1 = r1s*64 + (g1 ^ (r1s & 7))*8;

  for (int k0 = 0; k0 < K; k0 += 64){
    short8 a0 = *(const short8*)&A[aOff0 + k0];
    short8 a1 = *(const short8*)&A[aOff1 + k0];
    short8 b0 = *(const short8*)&B[bOff0 + k0];
    short8 b1 = *(const short8*)&B[bOff1 + k0];
    __syncthreads();
    *(short8*)&As[w0] = a0; *(short8*)&As[w1] = a1;
    *(short8*)&Bs[w0] = b0; *(short8*)&Bs[w1] = b1;
    __syncthreads();
    #pragma unroll
    for (int ks = 0; ks < 2; ks++){
      short8 af[2], bfr[2];
      #pragma unroll
      for (int mi = 0; mi < 2; mi++){
        int r = wm + mi*16 + l16;
        int pos = ((ks << 2) + quad) ^ (r & 7);
        af[mi] = *(const short8*)&As[r*64 + pos*8];
      }
      #pragma unroll
      for (int ni = 0; ni < 2; ni++){
        int r = wn + ni*16 + l16;
        int pos = ((ks << 2) + quad) ^ (r & 7);
        bfr[ni] = *(const short8*)&Bs[r*64 + pos*8];
      }
      #pragma unroll
      for (int mi = 0; mi < 2; mi++)
        #pragma unroll
        for (int ni = 0; ni < 2; ni++)
          acc[mi][ni] = __builtin_amdgcn_mfma_f32_16x16x32_bf16(af[mi], bfr[ni], acc[mi][ni], 0, 0, 0);
    }
  }
  #pragma unroll
  for (int mi = 0; mi < 2; mi++)
    #pragma unroll
    for (int ni = 0; ni < 2; ni++){
      int col = n0 + wn + ni*16 + l16;
      if (col >= N) continue;
      float bv = bias ? bias[col] : 0.f;
      #pragma unroll
      for (int rr = 0; rr < 4; rr++){
        int row = m0 + wm + mi*16 + (quad << 2) + rr;
        float v = acc[mi][ni][rr] + bv;
        long idx = (long)row*N + col;
        if (outDual && f) ((unsigned short*)C)[idx] = f2b(v);
        else              ((float*)C)[idx] = v;
      }
    }
}

// ============ fused conv+dt+intra-chunk SSD (per c,h,b) ============
// conv/SiLU computed inline from ZX (sliding 4-tap window); then
// S = (coef.X)^T B, G = C.B^T (masked/exp), Y = G.X + D*x via MFMA.
__global__ __launch_bounds__(256) void k_scan1(
    const float* __restrict__ zx, const float* __restrict__ cw, const float* __restrict__ cbv,
    const float* __restrict__ dtb, const float* __restrict__ alog, const float* __restrict__ dvec,
    float* __restrict__ S, float* __restrict__ LAb, unsigned short* __restrict__ CbS,
    float* __restrict__ y)
{
  int c = blockIdx.x, h = blockIdx.y, b = blockIdx.z;
  int t = threadIdx.x, w = t >> 6, lane = t & 63;
  int quad = lane >> 4, l16 = lane & 15;
  int l0 = c*QCH;
  __shared__ unsigned short XT[64*40];    // XT[p][j] = X[j][p]
  __shared__ unsigned short BTc[128*40];  // BTc[n][j] = coef[j]*B[j][n]
  __shared__ unsigned short Bb[32*136];   // B[j][n]
  __shared__ unsigned short Cb[32*136];   // C[j][n]
  __shared__ unsigned short Gb[32*40];    // G[i][j]
  __shared__ float dtl[32], lal[32], coef[32];
  float A  = -__expf(alog[h]);
  float Dv = dvec[h];

  // ---- dt softplus + prefix ----
  if (t < 32){
    float v = zx[(long)(b*L_SEQ + l0 + t)*DINPROJ + 2304 + h] + dtb[h];
    dtl[t] = (v > 20.f) ? v : log1pf(__expf(v));
  }
  __syncthreads();
  if (t == 0){ float s = 0.f; for (int i = 0; i < 32; i++){ s += dtl[i]; lal[i] = s*A; } }
  __syncthreads();
  if (t < 32){
    coef[t] = __expf(lal[31] - lal[t]) * dtl[t];
    LAb[(b*NHEADSM + h)*L_SEQ + l0 + t] = lal[t];
  }
  __syncthreads();

  // ---- conv + SiLU, sliding window ----
  // thread t: B/C col gcA = 2048 + t (conv col 1024+t); t<64 also x col gcB = 1024+h*64+t
  int ccA = 1024 + t;
  float cwA0 = cw[ccA*4], cwA1 = cw[ccA*4+1], cwA2 = cw[ccA*4+2], cwA3 = cw[ccA*4+3];
  float cbA = cbv[ccA];
  int gcA = 2048 + t;
  float w0A = 0.f, w1A = 0.f, w2A = 0.f;
  int ccB = h*64 + (t & 63);
  float cwB0 = cw[ccB*4], cwB1 = cw[ccB*4+1], cwB2 = cw[ccB*4+2], cwB3 = cw[ccB*4+3];
  float cbB = cbv[ccB];
  int gcB = 1024 + ccB;
  float w0B = 0.f, w1B = 0.f, w2B = 0.f;
  long rowBase = (long)(b*L_SEQ + l0)*DINPROJ;
  if (c > 0){
    w0A = zx[rowBase - 3*DINPROJ + gcA];
    w1A = zx[rowBase - 2*DINPROJ + gcA];
    w2A = zx[rowBase - 1*DINPROJ + gcA];
    if (t < 64){
      w0B = zx[rowBase - 3*DINPROJ + gcB];
      w1B = zx[rowBase - 2*DINPROJ + gcB];
      w2B = zx[rowBase - 1*DINPROJ + gcB];
    }
  }
  long cBase = ((long)((b*NHEADSM + h)*NCH + c))*4096;
  #pragma unroll 4
  for (int i = 0; i < 32; i++){
    long rb = rowBase + (long)i*DINPROJ;
    float zA = zx[rb + gcA];
    float sA = silu(cbA + cwA0*w0A + cwA1*w1A + cwA2*w2A + cwA3*zA);
    w0A = w1A; w1A = w2A; w2A = zA;
    if (t < 128){
      unsigned short bb = f2b(sA);
      Bb[i*136 + t] = bb;
      BTc[t*40 + i] = f2b(sA * coef[i]);
    } else {
      int n = t - 128;
      unsigned short cc = f2b(sA);
      Cb[i*136 + n] = cc;
      CbS[cBase + i*128 + n] = cc;
    }
    if (t < 64){
      float zB = zx[rb + gcB];
      float sB = silu(cbB + cwB0*w0B + cwB1*w1B + cwB2*w2B + cwB3*zB);
      w0B = w1B; w1B = w2B; w2B = zB;
      XT[t*40 + i] = f2b(sB);
    }
  }
  __syncthreads();

  // ---- S: wave w owns p-block w; 8 n-blocks ----
  short8 afS = *(const short8*)&XT[(w*16 + l16)*40 + quad*8];
  floatx4 accS[8];
  #pragma unroll
  for (int nb = 0; nb < 8; nb++){
    short8 bfS = *(const short8*)&BTc[(nb*16 + l16)*40 + quad*8];
    accS[nb] = __builtin_amdgcn_mfma_f32_16x16x32_bf16(afS, bfS, (floatx4){0.f,0.f,0.f,0.f}, 0, 0, 0);
  }
  // ---- G: wave w -> (ti = w&1, tj = w>>1) ----
  int ti = w & 1, tj = w >> 1;
  floatx4 accG = (floatx4){0.f,0.f,0.f,0.f};
  #pragma unroll
  for (int ks = 0; ks < 4; ks++){
    short8 ga = *(const short8*)&Cb[(ti*16 + l16)*136 + ks*32 + quad*8];
    short8 gb = *(const short8*)&Bb[(tj*16 + l16)*136 + ks*32 + quad*8];
    accG = __builtin_amdgcn_mfma_f32_16x16x32_bf16(ga, gb, accG, 0, 0, 0);
  }
  long sb = ((long)((b*NHEADSM + h)*NCH + c))*8192;
  #pragma unroll
  for (int nb = 0; nb < 8; nb++)
    #pragma unroll
    for (int rr = 0; rr < 4; rr++)
      S[sb + (w*16 + quad*4 + rr)*128 + nb*16 + l16] = accS[nb][rr];
  #pragma unroll
  for (int rr = 0; rr < 4; rr++){
    int i = ti*16 + quad*4 + rr, j = tj*16 + l16;
    float g = (j <= i) ? __expf(lal[i] - lal[j]) * dtl[j] * accG[rr] : 0.f;
    Gb[i*40 + j] = f2b(g);
  }
  __syncthreads();
  // ---- Y: wave w -> (ti = w&1, pb = (w>>1)*2 + s) ----
  short8 ag = *(const short8*)&Gb[(ti*16 + l16)*40 + quad*8];
  #pragma unroll
  for (int s = 0; s < 2; s++){
    int pb = (w >> 1)*2 + s;
    short8 bx = *(const short8*)&XT[(pb*16 + l16)*40 + quad*8];
    floatx4 accY = __builtin_amdgcn_mfma_f32_16x16x32_bf16(ag, bx, (floatx4){0.f,0.f,0.f,0.f}, 0, 0, 0);
    #pragma unroll
    for (int rr = 0; rr < 4; rr++){
      int i = ti*16 + quad*4 + rr, p = pb*16 + l16;
      float xval = b2f(XT[p*40 + i]);
      y[(long)(b*L_SEQ + l0 + i)*DINNER + h*64 + p] = fmaf(Dv, xval, accY[rr]);
    }
  }
}

// ============ fused inter-chunk state scan + output (per b,h) ============
// H kept in registers (32/thread); per chunk: stage H(hi/lo bf16)+C -> MFMA
// Y += el * C.H^T -> update H = H*lam + S[c].
__global__ __launch_bounds__(256) void k_scan2(
    const unsigned short* __restrict__ CbS, const float* __restrict__ S,
    const float* __restrict__ LAb, float* __restrict__ y)
{
  int h = blockIdx.x & 15, b = blockIdx.x >> 4;
  int t = threadIdx.x, w = t >> 6, lane = t & 63;
  int quad = lane >> 4, l16 = lane & 15;
  int bh = b*NHEADSM + h;
  __shared__ unsigned short Cb[32*136];
  __shared__ unsigned short Hhi[64*136];
  __shared__ unsigned short Hlo[64*136];
  __shared__ float el[32];
  float hreg[32];
  #pragma unroll
  for (int k = 0; k < 32; k++) hreg[k] = 0.f;
  long sBase = (long)bh*NCH*8192;
  long cBase = (long)bh*NCH*4096;
  int laBase = bh*L_SEQ;
  int ti = w & 1;
  for (int c = 0; c < NCH; c++){
    if (t < 32) el[t] = __expf(LAb[laBase + c*QCH + t]);
    #pragma unroll
    for (int k = 0; k < 16; k++){
      int idx = t + k*256; int j = idx >> 7, n = idx & 127;
      Cb[j*136 + n] = CbS[cBase + c*4096 + idx];
    }
    #pragma unroll
    for (int k = 0; k < 32; k++){
      int idx = t + k*256; int p = idx >> 7, n = idx & 127;
      float v = hreg[k];
      unsigned short hi = f2b(v);
      Hhi[p*136 + n] = hi;
      Hlo[p*136 + n] = f2b(v - b2f(hi));
    }
    __syncthreads();
    int l0 = c*QCH;
    #pragma unroll
    for (int s = 0; s < 2; s++){
      int pb = (w >> 1)*2 + s;
      floatx4 acc = (floatx4){0.f,0.f,0.f,0.f};
      #pragma unroll
      for (int ks = 0; ks < 4; ks++){
        short8 a  = *(const short8*)&Cb [(ti*16 + l16)*136 + ks*32 + quad*8];
        short8 bl = *(const short8*)&Hlo[(pb*16 + l16)*136 + ks*32 + quad*8];
        short8 bhv= *(const short8*)&Hhi[(pb*16 + l16)*136 + ks*32 + quad*8];
        acc = __builtin_amdgcn_mfma_f32_16x16x32_bf16(a, bl, acc, 0, 0, 0);
        acc = __builtin_amdgcn_mfma_f32_16x16x32_bf16(a, bhv, acc, 0, 0, 0);
      }
      #pragma unroll
      for (int rr = 0; rr < 4; rr++){
        int i = ti*16 + quad*4 + rr, p = pb*16 + l16;
        long yb = (long)(b*L_SEQ + l0 + i)*DINNER + h*64 + p;
        y[yb] = fmaf(el[i], acc[rr], y[yb]);
      }
    }
    float lam = __expf(LAb[laBase + c*QCH + QCH - 1]);
    #pragma unroll
    for (int k = 0; k < 32; k++){
      float sv = S[sBase + (long)c*8192 + t + k*256];
      hreg[k] = fmaf(hreg[k], lam, sv);
    }
    __syncthreads();
  }
}

__global__ __launch_bounds__(256) void k_gated_rms(
    const float* __restrict__ y, const float* __restrict__ zx, const float* __restrict__ rw,
    unsigned short* __restrict__ ybf)
{
  int r = blockIdx.x, t = threadIdx.x;
  float g[4]; float ss = 0.f;
  #pragma unroll
  for (int i = 0; i < 4; i++){
    int c = t + i*256;
    float z  = zx[(long)r*DINPROJ + c];
    float yv = y[(long)r*DINNER + c];
    g[i] = yv * silu(z);
    ss = fmaf(g[i], g[i], ss);
  }
  #pragma unroll
  for (int o = 1; o < 64; o <<= 1) ss += __shfl_xor(ss, o);
  __shared__ float red[4];
  int w = t >> 6, lane = t & 63;
  if (lane == 0) red[w] = ss;
  __syncthreads();
  float tot = red[0] + red[1] + red[2] + red[3];
  float sc = rsqrtf(tot / (float)DINNER + 1e-5f);
  #pragma unroll
  for (int i = 0; i < 4; i++){
    int c = t + i*256;
    ybf[(long)r*DINNER + c] = f2b(g[i] * sc * rw[c]);
  }
}

__global__ __launch_bounds__(256) void k_add_ln(
    float* __restrict__ x, const float* __restrict__ o,
    const float* __restrict__ lw, const float* __restrict__ lb,
    unsigned short* __restrict__ xbf)
{
  int r = blockIdx.x, t = threadIdx.x;
  float v[2]; float sm = 0.f;
  #pragma unroll
  for (int i = 0; i < 2; i++){ int c = t + i*256; v[i] = x[(long)r*DMODEL + c] + o[(long)r*DMODEL + c]; sm += v[i]; }
  #pragma unroll
  for (int off = 1; off < 64; off <<= 1) sm += __shfl_xor(sm, off);
  __shared__ float red[4]; __shared__ float red2[4];
  int w = t >> 6, lane = t & 63;
  if (lane == 0) red[w] = sm;
  __syncthreads();
  float mu = (red[0] + red[1] + red[2] + red[3]) / (float)DMODEL;
  float var = 0.f;
  #pragma unroll
  for (int i = 0; i < 2; i++){ v[i] -= mu; var = fmaf(v[i], v[i], var); }
  #pragma unroll
  for (int off = 1; off < 64; off <<= 1) var += __shfl_xor(var, off);
  if (lane == 0) red2[w] = var;
  __syncthreads();
  float vv = (red2[0] + red2[1] + red2[2] + red2[3]) / (float)DMODEL;
  float sc = rsqrtf(vv + 1e-5f);
  #pragma unroll
  for (int i = 0; i < 2; i++){
    int c = t + i*256;
    float ov = v[i]*sc*lw[c] + lb[c];
    x[(long)r*DMODEL + c] = ov;
    xbf[(long)r*DMODEL + c] = f2b(ov);
  }
}

extern "C" void kernel_launch(void* const* d_in, const int* in_sizes, int n_in,
                              void* d_out, int out_size, void* d_ws, size_t ws_size,
                              hipStream_t stream)
{
  const int* tokens = (const int*)d_in[0];
  const void* emb = d_in[1];
  int* flag = (int*)d_ws;
  float* ws = (float*)((char*)d_ws + 256);

  k_detect<<<1, 256, 0, stream>>>((const unsigned*)emb, flag);

  ConvArgs ca;
  const int sizes[9] = {10240, 2560, 32, 32, 32, 2048, 1024, 1024, 1000};
  const int idxs[9]  = {3, 4, 5, 6, 7, 8, 10, 11, 13};
  int off = 0;
  for (int s = 0; s < 9; s++){ ca.src[s] = d_in[idxs[s]]; ca.off[s] = off; off += sizes[s]; }
  ca.off[9] = off;

  float* X  = ws + O_X;
  float* ZX = ws + O_ZX;
  float* Y  = ws + O_Y;
  float* Ob = ws + O_O;
  float* LA = ws + O_LA;
  float* Sb = ws + O_S;
  unsigned short* CbS = (unsigned short*)(ws + O_XC);
  unsigned short* ub  = (unsigned short*)(ws + O_UB);
  unsigned short* WiB = ub + U_WI;
  unsigned short* WoB = ub + U_WO;
  unsigned short* WhB = ub + U_WH;
  unsigned short* Xbf = ub + U_XBF;
  unsigned short* Ybf = ub + U_YBF;

  k_prep<<<71 + NPREPW + NROWS, 256, 0, stream>>>(
      ca, d_in[2], d_in[9], d_in[12], tokens, emb, flag,
      ws, WiB, WoB, WhB, X, Xbf);

  for (int layer = 0; layer < 2; layer++){
    k_mfma_nt<<<dim3(WI_PAD/64, NROWS/64), 256, 0, stream>>>(
        Xbf, WiB + (long)layer*WI_PAD*DMODEL, (void*)ZX,
        NROWS, DINPROJ, DMODEL, (const float*)nullptr, flag, 0);
    k_scan1<<<dim3(NCH, NHEADSM, BATCH), 256, 0, stream>>>(
        ZX, ws + W_CONVW + layer*5120, ws + W_CONVB + layer*1280, ws + W_DTB + layer*16,
        ws + W_ALOG + layer*16, ws + W_DD + layer*16, Sb, LA, CbS, Y);
    k_scan2<<<BATCH*NHEADSM, 256, 0, stream>>>(CbS, Sb, LA, Y);
    k_gated_rms<<<NROWS, 256, 0, stream>>>(Y, ZX, ws + W_RMSW + layer*1024, Ybf);
    k_mfma_nt<<<dim3(DMODEL/64, NROWS/64), 256, 0, stream>>>(
        Ybf, WoB + (long)layer*DMODEL*DINNER, (void*)Ob,
        NROWS, DMODEL, DINNER, (const float*)nullptr, flag, 0);
    k_add_ln<<<NROWS, 256, 0, stream>>>(X, Ob, ws + W_LNW + layer*512, ws + W_LNB + layer*512, Xbf);
  }

  k_mfma_nt<<<dim3(WH_PAD/64, NROWS/64), 256, 0, stream>>>(
      Xbf, WhB, d_out, NROWS, 1000, DMODEL, ws + W_HEADB, flag, 1);
}

// Round 7
// 273.981 us; speedup vs baseline: 1.7515x; 1.7515x over previous
//
#include <hip/hip_runtime.h>

#define L_SEQ 512
#define BATCH 2
#define NROWS (BATCH*L_SEQ)   // 1024
#define DMODEL 512
#define DINNER 1024
#define DSTATE 128
#define NHEADSM 16
#define CONVD 1280
#define DINPROJ 2320
#define QCH 32
#define NCH 16
#define WI_PAD 2368           // 2320 padded to x64
#define WH_PAD 1024           // 1000 padded to x64

// ws float offsets (after 256B header holding the dtype flag)
#define W_CONVW 0
#define W_CONVB 10240
#define W_DTB   12800
#define W_ALOG  12832
#define W_DD    12864
#define W_RMSW  12896
#define W_LNW   14944
#define W_LNB   15968
#define W_HEADB 16992
#define O_X     18048
#define O_ZX    (O_X  + NROWS*DMODEL)
#define O_XC    (O_ZX + NROWS*DINPROJ)   // reused: CbS bf16 region (4 MB)
#define O_DT    (O_XC + NROWS*CONVD)
#define O_Y     (O_DT + NROWS*NHEADSM)
#define O_O     (O_Y  + NROWS*DINNER)
#define O_LA    (O_O  + NROWS*DMODEL)
#define O_S     (O_LA + 16384)
#define O_UB    (O_S  + 4194304)
// ushort offsets within bf16 region:
#define U_WI   0
#define U_WO   2424832
#define U_WH   3473408
#define U_XBF  3997696
#define U_YBF  4521984

#define NPREPW (2*WI_PAD + 2*DMODEL + WH_PAD)   // 6848 weight rows

typedef __attribute__((ext_vector_type(8))) short short8;
typedef __attribute__((ext_vector_type(4))) float floatx4;

__device__ __forceinline__ float b2f(unsigned short h){ return __uint_as_float(((unsigned)h)<<16); }
__device__ __forceinline__ unsigned short f2b(float x){
  unsigned u = __float_as_uint(x);
  return (unsigned short)((u + 0x7fffu + ((u>>16)&1u)) >> 16);
}
__device__ __forceinline__ float loadIn(const void* p, long i, int f){
  return f ? b2f(((const unsigned short*)p)[i]) : ((const float*)p)[i];
}
__device__ __forceinline__ float silu(float s){ return s / (1.f + __expf(-s)); }

// ---- dtype detect: low-16 of f32 words are a bf16 value iff data is packed bf16 ----
__global__ void k_detect(const unsigned* __restrict__ emb, int* __restrict__ flag){
  __shared__ int red[256];
  int t = threadIdx.x; int cnt = 0;
  for (int i = 0; i < 16; i++){
    unsigned w = emb[t*16 + i];
    unsigned e = (w >> 7) & 0xffu;
    cnt += (e >= 100 && e <= 126) ? 1 : 0;
  }
  red[t] = cnt; __syncthreads();
  if (t == 0){
    int s = 0;
    for (int i = 0; i < 256; i++) s += red[i];
    *flag = (s > 2048) ? 1 : 0;
  }
}

struct ConvArgs { const void* src[9]; int off[10]; };

// fused startup: small-param convert + weight bf16 prep + embedding
__global__ void k_prep(ConvArgs a, const void* __restrict__ wi, const void* __restrict__ wo,
                       const void* __restrict__ wh, const int* __restrict__ tok,
                       const void* __restrict__ emb, const int* __restrict__ flag,
                       float* __restrict__ dstSmall,
                       unsigned short* __restrict__ WiB, unsigned short* __restrict__ WoB,
                       unsigned short* __restrict__ WhB,
                       float* __restrict__ x, unsigned short* __restrict__ xbf)
{
  int f = *flag;
  int blk = blockIdx.x;
  if (blk < 71){
    int i = blk*256 + threadIdx.x;
    if (i < a.off[9]){
      int s = 0;
      while (i >= a.off[s+1]) s++;
      dstSmall[i] = loadIn(a.src[s], i - a.off[s], f);
    }
    return;
  }
  blk -= 71;
  if (blk < NPREPW){
    int r = blk;
    const void* src = nullptr; unsigned short* dst; long sb = 0, db; int K; bool zero = false;
    if (r < 2*WI_PAD){
      int layer = r / WI_PAD, row = r % WI_PAD;
      K = DMODEL; dst = WiB; db = ((long)layer*WI_PAD + row)*DMODEL;
      if (row < DINPROJ){ src = wi; sb = ((long)layer*DINPROJ + row)*DMODEL; } else zero = true;
    } else if (r < 2*WI_PAD + 2*DMODEL){
      int rr = r - 2*WI_PAD;
      K = DINNER; dst = WoB; db = (long)rr*DINNER;
      src = wo; sb = db;
    } else {
      int row = r - 2*WI_PAD - 2*DMODEL;
      K = DMODEL; dst = WhB; db = (long)row*DMODEL;
      if (row < 1000){ src = wh; sb = db; } else zero = true;
    }
    for (int c = threadIdx.x; c < K; c += 256)
      dst[db + c] = zero ? (unsigned short)0
                         : (f ? ((const unsigned short*)src)[sb + c] : f2b(((const float*)src)[sb + c]));
    return;
  }
  int r = blk - NPREPW;   // embed row
  long base = (long)tok[r] * DMODEL;
  for (int c = threadIdx.x; c < DMODEL; c += 256){
    float v = loadIn(emb, base + c, f);
    x[(long)r*DMODEL + c] = v;
    xbf[(long)r*DMODEL + c] = f ? ((const unsigned short*)emb)[base + c] : f2b(v);
  }
}

// ======== bf16 MFMA GEMM: C[M,N] = A[M,K] @ B[N,K]^T (+bias) ========
__global__ __launch_bounds__(256) void k_mfma_nt(
    const unsigned short* __restrict__ A, const unsigned short* __restrict__ B,
    void* __restrict__ C, int M, int N, int K,
    const float* __restrict__ bias, const int* __restrict__ flag, int outDual)
{
  __shared__ unsigned short As[4096];
  __shared__ unsigned short Bs[4096];
  int f = *flag;
  int t = threadIdx.x;
  int w = t >> 6, lane = t & 63;
  int quad = lane >> 4, l16 = lane & 15;
  int m0 = blockIdx.y << 6, n0 = blockIdx.x << 6;
  int wm = (w & 1) << 5, wn = (w >> 1) << 5;
  floatx4 acc[2][2];
  #pragma unroll
  for (int mi = 0; mi < 2; mi++)
    #pragma unroll
    for (int ni = 0; ni < 2; ni++) acc[mi][ni] = (floatx4){0.f,0.f,0.f,0.f};

  int idx0 = (w << 7) + lane;
  int r0s = idx0 >> 3, g0 = idx0 & 7;
  int idx1 = idx0 + 64;
  int r1s = idx1 >> 3, g1 = idx1 & 7;
  long aOff0 = (long)(m0 + r0s)*K + g0*8;
  long aOff1 = (long)(m0 + r1s)*K + g1*8;
  long bOff0 = (long)(n0 + r0s)*K + g0*8;
  long bOff1 = (long)(n0 + r1s)*K + g1*8;
  int w0 = r0s*64 + (g0 ^ (r0s & 7))*8;
  int w1 = r1s*64 + (g1 ^ (r1s & 7))*8;

  for (int k0 = 0; k0 < K; k0 += 64){
    short8 a0 = *(const short8*)&A[aOff0 + k0];
    short8 a1 = *(const short8*)&A[aOff1 + k0];
    short8 b0 = *(const short8*)&B[bOff0 + k0];
    short8 b1 = *(const short8*)&B[bOff1 + k0];
    __syncthreads();
    *(short8*)&As[w0] = a0; *(short8*)&As[w1] = a1;
    *(short8*)&Bs[w0] = b0; *(short8*)&Bs[w1] = b1;
    __syncthreads();
    #pragma unroll
    for (int ks = 0; ks < 2; ks++){
      short8 af[2], bfr[2];
      #pragma unroll
      for (int mi = 0; mi < 2; mi++){
        int r = wm + mi*16 + l16;
        int pos = ((ks << 2) + quad) ^ (r & 7);
        af[mi] = *(const short8*)&As[r*64 + pos*8];
      }
      #pragma unroll
      for (int ni = 0; ni < 2; ni++){
        int r = wn + ni*16 + l16;
        int pos = ((ks << 2) + quad) ^ (r & 7);
        bfr[ni] = *(const short8*)&Bs[r*64 + pos*8];
      }
      #pragma unroll
      for (int mi = 0; mi < 2; mi++)
        #pragma unroll
        for (int ni = 0; ni < 2; ni++)
          acc[mi][ni] = __builtin_amdgcn_mfma_f32_16x16x32_bf16(af[mi], bfr[ni], acc[mi][ni], 0, 0, 0);
    }
  }
  #pragma unroll
  for (int mi = 0; mi < 2; mi++)
    #pragma unroll
    for (int ni = 0; ni < 2; ni++){
      int col = n0 + wn + ni*16 + l16;
      if (col >= N) continue;
      float bv = bias ? bias[col] : 0.f;
      #pragma unroll
      for (int rr = 0; rr < 4; rr++){
        int row = m0 + wm + mi*16 + (quad << 2) + rr;
        float v = acc[mi][ni][rr] + bv;
        long idx = (long)row*N + col;
        if (outDual && f) ((unsigned short*)C)[idx] = f2b(v);
        else              ((float*)C)[idx] = v;
      }
    }
}

// ============ fused conv+dt+intra-chunk SSD (per c,h,b) ============
__global__ __launch_bounds__(256) void k_scan1(
    const float* __restrict__ zx, const float* __restrict__ cw, const float* __restrict__ cbv,
    const float* __restrict__ dtb, const float* __restrict__ alog, const float* __restrict__ dvec,
    float* __restrict__ S, float* __restrict__ LAb, unsigned short* __restrict__ CbS,
    float* __restrict__ y)
{
  int c = blockIdx.x, h = blockIdx.y, b = blockIdx.z;
  int t = threadIdx.x, w = t >> 6, lane = t & 63;
  int quad = lane >> 4, l16 = lane & 15;
  int l0 = c*QCH;
  __shared__ unsigned short XT[64*40];    // XT[p][j] = X[j][p]
  __shared__ unsigned short BTc[128*40];  // BTc[n][j] = coef[j]*B[j][n]
  __shared__ unsigned short Bb[32*136];   // B[j][n]
  __shared__ unsigned short Cb[32*136];   // C[j][n]
  __shared__ unsigned short Gb[32*40];    // G[i][j]
  __shared__ float dtl[32], lal[32], coef[32];
  float A  = -__expf(alog[h]);
  float Dv = dvec[h];

  // ---- dt softplus + prefix ----
  if (t < 32){
    float v = zx[(long)(b*L_SEQ + l0 + t)*DINPROJ + 2304 + h] + dtb[h];
    dtl[t] = (v > 20.f) ? v : log1pf(__expf(v));
  }
  __syncthreads();
  if (t == 0){ float s = 0.f; for (int i = 0; i < 32; i++){ s += dtl[i]; lal[i] = s*A; } }
  __syncthreads();
  if (t < 32){
    coef[t] = __expf(lal[31] - lal[t]) * dtl[t];
    LAb[(b*NHEADSM + h)*L_SEQ + l0 + t] = lal[t];
  }
  __syncthreads();

  // ---- conv + SiLU, sliding window ----
  int ccA = 1024 + t;
  float cwA0 = cw[ccA*4], cwA1 = cw[ccA*4+1], cwA2 = cw[ccA*4+2], cwA3 = cw[ccA*4+3];
  float cbA = cbv[ccA];
  int gcA = 2048 + t;
  float w0A = 0.f, w1A = 0.f, w2A = 0.f;
  int ccB = h*64 + (t & 63);
  float cwB0 = cw[ccB*4], cwB1 = cw[ccB*4+1], cwB2 = cw[ccB*4+2], cwB3 = cw[ccB*4+3];
  float cbB = cbv[ccB];
  int gcB = 1024 + ccB;
  float w0B = 0.f, w1B = 0.f, w2B = 0.f;
  long rowBase = (long)(b*L_SEQ + l0)*DINPROJ;
  if (c > 0){
    w0A = zx[rowBase - 3*DINPROJ + gcA];
    w1A = zx[rowBase - 2*DINPROJ + gcA];
    w2A = zx[rowBase - 1*DINPROJ + gcA];
    if (t < 64){
      w0B = zx[rowBase - 3*DINPROJ + gcB];
      w1B = zx[rowBase - 2*DINPROJ + gcB];
      w2B = zx[rowBase - 1*DINPROJ + gcB];
    }
  }
  long cBase = ((long)((b*NHEADSM + h)*NCH + c))*4096;
  #pragma unroll 4
  for (int i = 0; i < 32; i++){
    long rb = rowBase + (long)i*DINPROJ;
    float zA = zx[rb + gcA];
    float sA = silu(cbA + cwA0*w0A + cwA1*w1A + cwA2*w2A + cwA3*zA);
    w0A = w1A; w1A = w2A; w2A = zA;
    if (t < 128){
      unsigned short bb = f2b(sA);
      Bb[i*136 + t] = bb;
      BTc[t*40 + i] = f2b(sA * coef[i]);
    } else {
      int n = t - 128;
      unsigned short cc = f2b(sA);
      Cb[i*136 + n] = cc;
      CbS[cBase + i*128 + n] = cc;
    }
    if (t < 64){
      float zB = zx[rb + gcB];
      float sB = silu(cbB + cwB0*w0B + cwB1*w1B + cwB2*w2B + cwB3*zB);
      w0B = w1B; w1B = w2B; w2B = zB;
      XT[t*40 + i] = f2b(sB);
    }
  }
  __syncthreads();

  // ---- S: wave w owns p-block w; 8 n-blocks ----
  short8 afS = *(const short8*)&XT[(w*16 + l16)*40 + quad*8];
  floatx4 accS[8];
  #pragma unroll
  for (int nb = 0; nb < 8; nb++){
    short8 bfS = *(const short8*)&BTc[(nb*16 + l16)*40 + quad*8];
    accS[nb] = __builtin_amdgcn_mfma_f32_16x16x32_bf16(afS, bfS, (floatx4){0.f,0.f,0.f,0.f}, 0, 0, 0);
  }
  // ---- G: wave w -> (ti = w&1, tj = w>>1) ----
  int ti = w & 1, tj = w >> 1;
  floatx4 accG = (floatx4){0.f,0.f,0.f,0.f};
  #pragma unroll
  for (int ks = 0; ks < 4; ks++){
    short8 ga = *(const short8*)&Cb[(ti*16 + l16)*136 + ks*32 + quad*8];
    short8 gb = *(const short8*)&Bb[(tj*16 + l16)*136 + ks*32 + quad*8];
    accG = __builtin_amdgcn_mfma_f32_16x16x32_bf16(ga, gb, accG, 0, 0, 0);
  }
  long sb = ((long)((b*NHEADSM + h)*NCH + c))*8192;
  #pragma unroll
  for (int nb = 0; nb < 8; nb++)
    #pragma unroll
    for (int rr = 0; rr < 4; rr++)
      S[sb + (w*16 + quad*4 + rr)*128 + nb*16 + l16] = accS[nb][rr];
  #pragma unroll
  for (int rr = 0; rr < 4; rr++){
    int i = ti*16 + quad*4 + rr, j = tj*16 + l16;
    float g = (j <= i) ? __expf(lal[i] - lal[j]) * dtl[j] * accG[rr] : 0.f;
    Gb[i*40 + j] = f2b(g);
  }
  __syncthreads();
  // ---- Y: wave w -> (ti = w&1, pb = (w>>1)*2 + s) ----
  short8 ag = *(const short8*)&Gb[(ti*16 + l16)*40 + quad*8];
  #pragma unroll
  for (int s = 0; s < 2; s++){
    int pb = (w >> 1)*2 + s;
    short8 bx = *(const short8*)&XT[(pb*16 + l16)*40 + quad*8];
    floatx4 accY = __builtin_amdgcn_mfma_f32_16x16x32_bf16(ag, bx, (floatx4){0.f,0.f,0.f,0.f}, 0, 0, 0);
    #pragma unroll
    for (int rr = 0; rr < 4; rr++){
      int i = ti*16 + quad*4 + rr, p = pb*16 + l16;
      float xval = b2f(XT[p*40 + i]);
      y[(long)(b*L_SEQ + l0 + i)*DINNER + h*64 + p] = fmaf(Dv, xval, accY[rr]);
    }
  }
}

// chunk2: state propagation, IN-PLACE, one thread per state element (1024 blocks).
__global__ __launch_bounds__(256) void k_chunk2(
    float* __restrict__ S, const float* __restrict__ LAb)
{
  int bh = blockIdx.x >> 5;
  int e = ((blockIdx.x & 31) << 8) + threadIdx.x;
  long base = (long)bh*NCH*8192 + e;
  int laBase = bh*L_SEQ;
  float lam[NCH];
  #pragma unroll
  for (int c = 0; c < NCH; c++) lam[c] = __expf(LAb[laBase + c*QCH + QCH - 1]);
  float hr = 0.f;
  #pragma unroll
  for (int c = 0; c < NCH; c++){
    long off = base + (long)c*8192;
    float sv = S[off];
    S[off] = hr;
    hr = fmaf(hr, lam[c], sv);
  }
}

// chunk3: Y += exp(la_i) * C.H^T  [32x64, K=128] via MFMA; C from bf16 stash, H double-bf16.
__global__ __launch_bounds__(256) void k_chunk3(
    const unsigned short* __restrict__ CbS, const float* __restrict__ H,
    const float* __restrict__ LAb, float* __restrict__ y)
{
  int c = blockIdx.x, h = blockIdx.y, b = blockIdx.z;
  int t = threadIdx.x, w = t >> 6, lane = t & 63;
  int quad = lane >> 4, l16 = lane & 15;
  int l0 = c*QCH, bh = b*NHEADSM + h;
  __shared__ unsigned short Cb[32*136];
  __shared__ unsigned short Hhi[64*136];
  __shared__ unsigned short Hlo[64*136];
  __shared__ float el[32];
  if (t < 32) el[t] = __expf(LAb[bh*L_SEQ + l0 + t]);
  long cBase = ((long)(bh*NCH + c))*4096;
  #pragma unroll
  for (int k = 0; k < 16; k++){
    int idx = t + k*256; int j = idx >> 7, n = idx & 127;
    Cb[j*136 + n] = CbS[cBase + idx];
  }
  long hb = ((long)(bh*NCH + c))*8192;
  #pragma unroll
  for (int k = 0; k < 32; k++){
    int idx = t + k*256; int p = idx >> 7, n = idx & 127;
    float v = H[hb + idx];
    unsigned short hi = f2b(v);
    Hhi[p*136 + n] = hi;
    Hlo[p*136 + n] = f2b(v - b2f(hi));
  }
  __syncthreads();
  int ti = w & 1;
  #pragma unroll
  for (int s = 0; s < 2; s++){
    int pb = (w >> 1)*2 + s;
    floatx4 acc = (floatx4){0.f,0.f,0.f,0.f};
    #pragma unroll
    for (int ks = 0; ks < 4; ks++){
      short8 a  = *(const short8*)&Cb [(ti*16 + l16)*136 + ks*32 + quad*8];
      short8 bl = *(const short8*)&Hlo[(pb*16 + l16)*136 + ks*32 + quad*8];
      short8 bh2= *(const short8*)&Hhi[(pb*16 + l16)*136 + ks*32 + quad*8];
      acc = __builtin_amdgcn_mfma_f32_16x16x32_bf16(a, bl, acc, 0, 0, 0);
      acc = __builtin_amdgcn_mfma_f32_16x16x32_bf16(a, bh2, acc, 0, 0, 0);
    }
    #pragma unroll
    for (int rr = 0; rr < 4; rr++){
      int i = ti*16 + quad*4 + rr, p = pb*16 + l16;
      long yb = (long)(b*L_SEQ + l0 + i)*DINNER + h*64 + p;
      y[yb] = fmaf(el[i], acc[rr], y[yb]);
    }
  }
}

__global__ __launch_bounds__(256) void k_gated_rms(
    const float* __restrict__ y, const float* __restrict__ zx, const float* __restrict__ rw,
    unsigned short* __restrict__ ybf)
{
  int r = blockIdx.x, t = threadIdx.x;
  float g[4]; float ss = 0.f;
  #pragma unroll
  for (int i = 0; i < 4; i++){
    int c = t + i*256;
    float z  = zx[(long)r*DINPROJ + c];
    float yv = y[(long)r*DINNER + c];
    g[i] = yv * silu(z);
    ss = fmaf(g[i], g[i], ss);
  }
  #pragma unroll
  for (int o = 1; o < 64; o <<= 1) ss += __shfl_xor(ss, o);
  __shared__ float red[4];
  int w = t >> 6, lane = t & 63;
  if (lane == 0) red[w] = ss;
  __syncthreads();
  float tot = red[0] + red[1] + red[2] + red[3];
  float sc = rsqrtf(tot / (float)DINNER + 1e-5f);
  #pragma unroll
  for (int i = 0; i < 4; i++){
    int c = t + i*256;
    ybf[(long)r*DINNER + c] = f2b(g[i] * sc * rw[c]);
  }
}

__global__ __launch_bounds__(256) void k_add_ln(
    float* __restrict__ x, const float* __restrict__ o,
    const float* __restrict__ lw, const float* __restrict__ lb,
    unsigned short* __restrict__ xbf)
{
  int r = blockIdx.x, t = threadIdx.x;
  float v[2]; float sm = 0.f;
  #pragma unroll
  for (int i = 0; i < 2; i++){ int c = t + i*256; v[i] = x[(long)r*DMODEL + c] + o[(long)r*DMODEL + c]; sm += v[i]; }
  #pragma unroll
  for (int off = 1; off < 64; off <<= 1) sm += __shfl_xor(sm, off);
  __shared__ float red[4]; __shared__ float red2[4];
  int w = t >> 6, lane = t & 63;
  if (lane == 0) red[w] = sm;
  __syncthreads();
  float mu = (red[0] + red[1] + red[2] + red[3]) / (float)DMODEL;
  float var = 0.f;
  #pragma unroll
  for (int i = 0; i < 2; i++){ v[i] -= mu; var = fmaf(v[i], v[i], var); }
  #pragma unroll
  for (int off = 1; off < 64; off <<= 1) var += __shfl_xor(var, off);
  if (lane == 0) red2[w] = var;
  __syncthreads();
  float vv = (red2[0] + red2[1] + red2[2] + red2[3]) / (float)DMODEL;
  float sc = rsqrtf(vv + 1e-5f);
  #pragma unroll
  for (int i = 0; i < 2; i++){
    int c = t + i*256;
    float ov = v[i]*sc*lw[c] + lb[c];
    x[(long)r*DMODEL + c] = ov;
    xbf[(long)r*DMODEL + c] = f2b(ov);
  }
}

extern "C" void kernel_launch(void* const* d_in, const int* in_sizes, int n_in,
                              void* d_out, int out_size, void* d_ws, size_t ws_size,
                              hipStream_t stream)
{
  const int* tokens = (const int*)d_in[0];
  const void* emb = d_in[1];
  int* flag = (int*)d_ws;
  float* ws = (float*)((char*)d_ws + 256);

  k_detect<<<1, 256, 0, stream>>>((const unsigned*)emb, flag);

  ConvArgs ca;
  const int sizes[9] = {10240, 2560, 32, 32, 32, 2048, 1024, 1024, 1000};
  const int idxs[9]  = {3, 4, 5, 6, 7, 8, 10, 11, 13};
  int off = 0;
  for (int s = 0; s < 9; s++){ ca.src[s] = d_in[idxs[s]]; ca.off[s] = off; off += sizes[s]; }
  ca.off[9] = off;

  float* X  = ws + O_X;
  float* ZX = ws + O_ZX;
  float* Y  = ws + O_Y;
  float* Ob = ws + O_O;
  float* LA = ws + O_LA;
  float* Sb = ws + O_S;
  unsigned short* CbS = (unsigned short*)(ws + O_XC);
  unsigned short* ub  = (unsigned short*)(ws + O_UB);
  unsigned short* WiB = ub + U_WI;
  unsigned short* WoB = ub + U_WO;
  unsigned short* WhB = ub + U_WH;
  unsigned short* Xbf = ub + U_XBF;
  unsigned short* Ybf = ub + U_YBF;

  k_prep<<<71 + NPREPW + NROWS, 256, 0, stream>>>(
      ca, d_in[2], d_in[9], d_in[12], tokens, emb, flag,
      ws, WiB, WoB, WhB, X, Xbf);

  for (int layer = 0; layer < 2; layer++){
    k_mfma_nt<<<dim3(WI_PAD/64, NROWS/64), 256, 0, stream>>>(
        Xbf, WiB + (long)layer*WI_PAD*DMODEL, (void*)ZX,
        NROWS, DINPROJ, DMODEL, (const float*)nullptr, flag, 0);
    k_scan1<<<dim3(NCH, NHEADSM, BATCH), 256, 0, stream>>>(
        ZX, ws + W_CONVW + layer*5120, ws + W_CONVB + layer*1280, ws + W_DTB + layer*16,
        ws + W_ALOG + layer*16, ws + W_DD + layer*16, Sb, LA, CbS, Y);
    k_chunk2<<<1024, 256, 0, stream>>>(Sb, LA);
    k_chunk3<<<dim3(NCH, NHEADSM, BATCH), 256, 0, stream>>>(CbS, Sb, LA, Y);
    k_gated_rms<<<NROWS, 256, 0, stream>>>(Y, ZX, ws + W_RMSW + layer*1024, Ybf);
    k_mfma_nt<<<dim3(DMODEL/64, NROWS/64), 256, 0, stream>>>(
        Ybf, WoB + (long)layer*DMODEL*DINNER, (void*)Ob,
        NROWS, DMODEL, DINNER, (const float*)nullptr, flag, 0);
    k_add_ln<<<NROWS, 256, 0, stream>>>(X, Ob, ws + W_LNW + layer*512, ws + W_LNB + layer*512, Xbf);
  }

  k_mfma_nt<<<dim3(WH_PAD/64, NROWS/64), 256, 0, stream>>>(
      Xbf, WhB, d_out, NROWS, 1000, DMODEL, ws + W_HEADB, flag, 1);
}

// Round 8
// 261.134 us; speedup vs baseline: 1.8376x; 1.0492x over previous
//
#include <hip/hip_runtime.h>

#define L_SEQ 512
#define BATCH 2
#define NROWS (BATCH*L_SEQ)   // 1024
#define DMODEL 512
#define DINNER 1024
#define DSTATE 128
#define NHEADSM 16
#define CONVD 1280
#define DINPROJ 2320
#define QCH 32
#define NCH 16
#define WI_PAD 2368           // 2320 padded to x64
#define WH_PAD 1024           // 1000 padded to x64

// ws float offsets (after 256B header holding the dtype flag)
#define W_CONVW 0
#define W_CONVB 10240
#define W_DTB   12800
#define W_ALOG  12832
#define W_DD    12864
#define W_RMSW  12896
#define W_LNW   14944
#define W_LNB   15968
#define W_HEADB 16992
#define O_X     18048
#define O_ZX    (O_X  + NROWS*DMODEL)
#define O_XC    (O_ZX + NROWS*DINPROJ)   // now bf16 XC (xcb), 2.6 MB of this region
#define O_DT    (O_XC + NROWS*CONVD)
#define O_Y     (O_DT + NROWS*NHEADSM)
#define O_O     (O_Y  + NROWS*DINNER)
#define O_LA    (O_O  + NROWS*DMODEL)
#define O_S     (O_LA + 16384)
#define O_UB    (O_S  + 4194304)
// ushort offsets within bf16 region:
#define U_WI   0
#define U_WO   2424832
#define U_WH   3473408
#define U_XBF  3997696
#define U_YBF  4521984

#define NPREPW (2*WI_PAD + 2*DMODEL + WH_PAD)   // 6848 weight rows

typedef __attribute__((ext_vector_type(8))) short short8;
typedef __attribute__((ext_vector_type(4))) float floatx4;

__device__ __forceinline__ float b2f(unsigned short h){ return __uint_as_float(((unsigned)h)<<16); }
__device__ __forceinline__ unsigned short f2b(float x){
  unsigned u = __float_as_uint(x);
  return (unsigned short)((u + 0x7fffu + ((u>>16)&1u)) >> 16);
}
__device__ __forceinline__ float loadIn(const void* p, long i, int f){
  return f ? b2f(((const unsigned short*)p)[i]) : ((const float*)p)[i];
}
__device__ __forceinline__ float silu(float s){ return s / (1.f + __expf(-s)); }

struct ConvArgs { const void* src[9]; int off[10]; };

// fused startup: self dtype-detect + small-param convert + weight bf16 prep + embedding
__global__ void k_prep(ConvArgs a, const void* __restrict__ wi, const void* __restrict__ wo,
                       const void* __restrict__ wh, const int* __restrict__ tok,
                       const void* __restrict__ emb, int* __restrict__ flagOut,
                       float* __restrict__ dstSmall,
                       unsigned short* __restrict__ WiB, unsigned short* __restrict__ WoB,
                       unsigned short* __restrict__ WhB,
                       float* __restrict__ x, unsigned short* __restrict__ xbf)
{
  // ---- self-detect: low-16 of f32 words are a plausible bf16 iff data is packed bf16 ----
  __shared__ int sflag;
  int t = threadIdx.x;
  if (t < 64){
    int cnt = 0;
    #pragma unroll 8
    for (int i = 0; i < 64; i++){
      unsigned w0 = ((const unsigned*)emb)[t + 64*i];   // coalesced
      unsigned e = (w0 >> 7) & 0xffu;
      cnt += (e >= 100 && e <= 126) ? 1 : 0;
    }
    #pragma unroll
    for (int o = 1; o < 64; o <<= 1) cnt += __shfl_xor(cnt, o);
    if (t == 0) sflag = (cnt > 2048) ? 1 : 0;
  }
  __syncthreads();
  int f = sflag;
  if (blockIdx.x == 0 && t == 0) *flagOut = f;

  int blk = blockIdx.x;
  if (blk < 71){
    int i = blk*256 + t;
    if (i < a.off[9]){
      int s = 0;
      while (i >= a.off[s+1]) s++;
      dstSmall[i] = loadIn(a.src[s], i - a.off[s], f);
    }
    return;
  }
  blk -= 71;
  if (blk < NPREPW){
    int r = blk;
    const void* src = nullptr; unsigned short* dst; long sb = 0, db; int K; bool zero = false;
    if (r < 2*WI_PAD){
      int layer = r / WI_PAD, row = r % WI_PAD;
      K = DMODEL; dst = WiB; db = ((long)layer*WI_PAD + row)*DMODEL;
      if (row < DINPROJ){ src = wi; sb = ((long)layer*DINPROJ + row)*DMODEL; } else zero = true;
    } else if (r < 2*WI_PAD + 2*DMODEL){
      int rr = r - 2*WI_PAD;
      K = DINNER; dst = WoB; db = (long)rr*DINNER;
      src = wo; sb = db;
    } else {
      int row = r - 2*WI_PAD - 2*DMODEL;
      K = DMODEL; dst = WhB; db = (long)row*DMODEL;
      if (row < 1000){ src = wh; sb = db; } else zero = true;
    }
    for (int c = t; c < K; c += 256)
      dst[db + c] = zero ? (unsigned short)0
                         : (f ? ((const unsigned short*)src)[sb + c] : f2b(((const float*)src)[sb + c]));
    return;
  }
  int r = blk - NPREPW;   // embed row
  long base = (long)tok[r] * DMODEL;
  for (int c = t; c < DMODEL; c += 256){
    float v = loadIn(emb, base + c, f);
    x[(long)r*DMODEL + c] = v;
    xbf[(long)r*DMODEL + c] = f ? ((const unsigned short*)emb)[base + c] : f2b(v);
  }
}

// ======== bf16 MFMA GEMM: C[M,N] = A[M,K] @ B[N,K]^T (+bias) ========
__global__ __launch_bounds__(256) void k_mfma_nt(
    const unsigned short* __restrict__ A, const unsigned short* __restrict__ B,
    void* __restrict__ C, int M, int N, int K,
    const float* __restrict__ bias, const int* __restrict__ flag, int outDual)
{
  __shared__ unsigned short As[4096];
  __shared__ unsigned short Bs[4096];
  int t = threadIdx.x;
  int w = t >> 6, lane = t & 63;
  int quad = lane >> 4, l16 = lane & 15;
  int m0 = blockIdx.y << 6, n0 = blockIdx.x << 6;
  int wm = (w & 1) << 5, wn = (w >> 1) << 5;
  floatx4 acc[2][2];
  #pragma unroll
  for (int mi = 0; mi < 2; mi++)
    #pragma unroll
    for (int ni = 0; ni < 2; ni++) acc[mi][ni] = (floatx4){0.f,0.f,0.f,0.f};

  int idx0 = (w << 7) + lane;
  int r0s = idx0 >> 3, g0 = idx0 & 7;
  int idx1 = idx0 + 64;
  int r1s = idx1 >> 3, g1 = idx1 & 7;
  long aOff0 = (long)(m0 + r0s)*K + g0*8;
  long aOff1 = (long)(m0 + r1s)*K + g1*8;
  long bOff0 = (long)(n0 + r0s)*K + g0*8;
  long bOff1 = (long)(n0 + r1s)*K + g1*8;
  int w0 = r0s*64 + (g0 ^ (r0s & 7))*8;
  int w1 = r1s*64 + (g1 ^ (r1s & 7))*8;

  for (int k0 = 0; k0 < K; k0 += 64){
    short8 a0 = *(const short8*)&A[aOff0 + k0];
    short8 a1 = *(const short8*)&A[aOff1 + k0];
    short8 b0 = *(const short8*)&B[bOff0 + k0];
    short8 b1 = *(const short8*)&B[bOff1 + k0];
    __syncthreads();
    *(short8*)&As[w0] = a0; *(short8*)&As[w1] = a1;
    *(short8*)&Bs[w0] = b0; *(short8*)&Bs[w1] = b1;
    __syncthreads();
    #pragma unroll
    for (int ks = 0; ks < 2; ks++){
      short8 af[2], bfr[2];
      #pragma unroll
      for (int mi = 0; mi < 2; mi++){
        int r = wm + mi*16 + l16;
        int pos = ((ks << 2) + quad) ^ (r & 7);
        af[mi] = *(const short8*)&As[r*64 + pos*8];
      }
      #pragma unroll
      for (int ni = 0; ni < 2; ni++){
        int r = wn + ni*16 + l16;
        int pos = ((ks << 2) + quad) ^ (r & 7);
        bfr[ni] = *(const short8*)&Bs[r*64 + pos*8];
      }
      #pragma unroll
      for (int mi = 0; mi < 2; mi++)
        #pragma unroll
        for (int ni = 0; ni < 2; ni++)
          acc[mi][ni] = __builtin_amdgcn_mfma_f32_16x16x32_bf16(af[mi], bfr[ni], acc[mi][ni], 0, 0, 0);
    }
  }
  int f = *flag;
  #pragma unroll
  for (int mi = 0; mi < 2; mi++)
    #pragma unroll
    for (int ni = 0; ni < 2; ni++){
      int col = n0 + wn + ni*16 + l16;
      if (col >= N) continue;
      float bv = bias ? bias[col] : 0.f;
      #pragma unroll
      for (int rr = 0; rr < 4; rr++){
        int row = m0 + wm + mi*16 + (quad << 2) + rr;
        float v = acc[mi][ni][rr] + bv;
        long idx = (long)row*N + col;
        if (outDual && f) ((unsigned short*)C)[idx] = f2b(v);
        else              ((float*)C)[idx] = v;
      }
    }
}

// conv + SiLU -> bf16 XC (xcb); dt softplus -> fp32 DT
__global__ __launch_bounds__(256) void k_conv_dt(
    const float* __restrict__ zx, const float* __restrict__ cw, const float* __restrict__ cb,
    const float* __restrict__ dtb, unsigned short* __restrict__ xcb, float* __restrict__ dt)
{
  int r = blockIdx.x; int b = r >> 9, l = r & 511;
  int t = threadIdx.x;
  for (int c = t; c < CONVD; c += 256){
    float s = cb[c];
    #pragma unroll
    for (int k = 0; k < 4; k++){
      int pos = l - 3 + k;
      if (pos >= 0)
        s = fmaf(zx[(long)(b*L_SEQ + pos)*DINPROJ + DINNER + c], cw[c*4 + k], s);
    }
    xcb[(long)r*CONVD + c] = f2b(silu(s));
  }
  if (t < NHEADSM){
    float v = zx[(long)r*DINPROJ + DINNER + CONVD + t] + dtb[t];
    dt[r*NHEADSM + t] = (v > 20.f) ? v : log1pf(__expf(v));  // softplus
  }
}

// ================= chunked SSD scan (MFMA, bf16 staging from xcb) =================
__global__ __launch_bounds__(256) void k_chunk1(
    const unsigned short* __restrict__ xcb, const float* __restrict__ dtbuf,
    const float* __restrict__ alog, const float* __restrict__ dvec,
    float* __restrict__ S, float* __restrict__ LAb, float* __restrict__ y)
{
  int c = blockIdx.x, h = blockIdx.y, b = blockIdx.z;
  int t = threadIdx.x, w = t >> 6, lane = t & 63;
  int quad = lane >> 4, l16 = lane & 15;
  int l0 = c*QCH;
  __shared__ unsigned short XT[64*40];    // XT[p][j] = X[j][p]
  __shared__ unsigned short BTc[128*40];  // BTc[n][j] = coef[j]*B[j][n]
  __shared__ unsigned short Bb[32*136];   // B[j][n]
  __shared__ unsigned short Cb[32*136];   // C[j][n]
  __shared__ unsigned short Gb[32*40];    // G[i][j]
  __shared__ float dtl[32], lal[32], coef[32];
  float A  = -__expf(alog[h]);
  float Dv = dvec[h];

  // prefetch bf16 tiles into regs (overlaps with dt prefix chain)
  unsigned short xus[8];
  #pragma unroll
  for (int k = 0; k < 8; k++){
    int idx = t + k*256; int j = idx >> 6, p = idx & 63;
    xus[k] = xcb[(long)(b*L_SEQ + l0 + j)*CONVD + h*64 + p];
  }
  unsigned short bus[16], cus[16];
  #pragma unroll
  for (int k = 0; k < 16; k++){
    int idx = t + k*256; int j = idx >> 7, n = idx & 127;
    long rb = (long)(b*L_SEQ + l0 + j)*CONVD + DINNER;
    bus[k] = xcb[rb + n];
    cus[k] = xcb[rb + DSTATE + n];
  }
  if (t < 32) dtl[t] = dtbuf[(b*L_SEQ + l0 + t)*NHEADSM + h];
  __syncthreads();
  if (t == 0){ float s = 0.f; for (int i = 0; i < 32; i++){ s += dtl[i]; lal[i] = s*A; } }
  __syncthreads();
  if (t < 32){
    coef[t] = __expf(lal[31] - lal[t]) * dtl[t];
    LAb[(b*NHEADSM + h)*L_SEQ + l0 + t] = lal[t];
  }
  __syncthreads();
  #pragma unroll
  for (int k = 0; k < 8; k++){
    int idx = t + k*256; int j = idx >> 6, p = idx & 63;
    XT[p*40 + j] = xus[k];
  }
  #pragma unroll
  for (int k = 0; k < 16; k++){
    int idx = t + k*256; int j = idx >> 7, n = idx & 127;
    Bb[j*136 + n] = bus[k];
    Cb[j*136 + n] = cus[k];
    BTc[n*40 + j] = f2b(b2f(bus[k]) * coef[j]);
  }
  __syncthreads();

  // ---- S: wave w owns p-block w; 8 n-blocks ----
  short8 afS = *(const short8*)&XT[(w*16 + l16)*40 + quad*8];
  floatx4 accS[8];
  #pragma unroll
  for (int nb = 0; nb < 8; nb++){
    short8 bfS = *(const short8*)&BTc[(nb*16 + l16)*40 + quad*8];
    accS[nb] = __builtin_amdgcn_mfma_f32_16x16x32_bf16(afS, bfS, (floatx4){0.f,0.f,0.f,0.f}, 0, 0, 0);
  }
  // ---- G: wave w -> (ti = w&1, tj = w>>1) ----
  int ti = w & 1, tj = w >> 1;
  floatx4 accG = (floatx4){0.f,0.f,0.f,0.f};
  #pragma unroll
  for (int ks = 0; ks < 4; ks++){
    short8 ga = *(const short8*)&Cb[(ti*16 + l16)*136 + ks*32 + quad*8];
    short8 gb = *(const short8*)&Bb[(tj*16 + l16)*136 + ks*32 + quad*8];
    accG = __builtin_amdgcn_mfma_f32_16x16x32_bf16(ga, gb, accG, 0, 0, 0);
  }
  long sb = ((long)((b*NHEADSM + h)*NCH + c))*8192;
  #pragma unroll
  for (int nb = 0; nb < 8; nb++)
    #pragma unroll
    for (int rr = 0; rr < 4; rr++)
      S[sb + (w*16 + quad*4 + rr)*128 + nb*16 + l16] = accS[nb][rr];
  #pragma unroll
  for (int rr = 0; rr < 4; rr++){
    int i = ti*16 + quad*4 + rr, j = tj*16 + l16;
    float g = (j <= i) ? __expf(lal[i] - lal[j]) * dtl[j] * accG[rr] : 0.f;
    Gb[i*40 + j] = f2b(g);
  }
  __syncthreads();
  // ---- Y: wave w -> (ti = w&1, pb = (w>>1)*2 + s) ----
  short8 ag = *(const short8*)&Gb[(ti*16 + l16)*40 + quad*8];
  #pragma unroll
  for (int s = 0; s < 2; s++){
    int pb = (w >> 1)*2 + s;
    short8 bx = *(const short8*)&XT[(pb*16 + l16)*40 + quad*8];
    floatx4 accY = __builtin_amdgcn_mfma_f32_16x16x32_bf16(ag, bx, (floatx4){0.f,0.f,0.f,0.f}, 0, 0, 0);
    #pragma unroll
    for (int rr = 0; rr < 4; rr++){
      int i = ti*16 + quad*4 + rr, p = pb*16 + l16;
      float xval = b2f(XT[p*40 + i]);
      y[(long)(b*L_SEQ + l0 + i)*DINNER + h*64 + p] = fmaf(Dv, xval, accY[rr]);
    }
  }
}

// chunk2: state propagation, IN-PLACE, one thread per state element (1024 blocks).
__global__ __launch_bounds__(256) void k_chunk2(
    float* __restrict__ S, const float* __restrict__ LAb)
{
  int bh = blockIdx.x >> 5;
  int e = ((blockIdx.x & 31) << 8) + threadIdx.x;
  long base = (long)bh*NCH*8192 + e;
  int laBase = bh*L_SEQ;
  float lam[NCH];
  #pragma unroll
  for (int c = 0; c < NCH; c++) lam[c] = __expf(LAb[laBase + c*QCH + QCH - 1]);
  float hr = 0.f;
  #pragma unroll
  for (int c = 0; c < NCH; c++){
    long off = base + (long)c*8192;
    float sv = S[off];
    S[off] = hr;
    hr = fmaf(hr, lam[c], sv);
  }
}

// chunk3: Y += exp(la_i) * C.H^T  [32x64, K=128] via MFMA; C from bf16 xcb, H double-bf16.
__global__ __launch_bounds__(256) void k_chunk3(
    const unsigned short* __restrict__ xcb, const float* __restrict__ H,
    const float* __restrict__ LAb, float* __restrict__ y)
{
  int c = blockIdx.x, h = blockIdx.y, b = blockIdx.z;
  int t = threadIdx.x, w = t >> 6, lane = t & 63;
  int quad = lane >> 4, l16 = lane & 15;
  int l0 = c*QCH, bh = b*NHEADSM + h;
  __shared__ unsigned short Cb[32*136];
  __shared__ unsigned short Hhi[64*136];
  __shared__ unsigned short Hlo[64*136];
  __shared__ float el[32];
  if (t < 32) el[t] = __expf(LAb[bh*L_SEQ + l0 + t]);
  #pragma unroll
  for (int k = 0; k < 16; k++){
    int idx = t + k*256; int j = idx >> 7, n = idx & 127;
    Cb[j*136 + n] = xcb[(long)(b*L_SEQ + l0 + j)*CONVD + DINNER + DSTATE + n];
  }
  long hb = ((long)(bh*NCH + c))*8192;
  #pragma unroll
  for (int k = 0; k < 32; k++){
    int idx = t + k*256; int p = idx >> 7, n = idx & 127;
    float v = H[hb + idx];
    unsigned short hi = f2b(v);
    Hhi[p*136 + n] = hi;
    Hlo[p*136 + n] = f2b(v - b2f(hi));
  }
  __syncthreads();
  int ti = w & 1;
  #pragma unroll
  for (int s = 0; s < 2; s++){
    int pb = (w >> 1)*2 + s;
    floatx4 acc = (floatx4){0.f,0.f,0.f,0.f};
    #pragma unroll
    for (int ks = 0; ks < 4; ks++){
      short8 a  = *(const short8*)&Cb [(ti*16 + l16)*136 + ks*32 + quad*8];
      short8 bl = *(const short8*)&Hlo[(pb*16 + l16)*136 + ks*32 + quad*8];
      short8 bh2= *(const short8*)&Hhi[(pb*16 + l16)*136 + ks*32 + quad*8];
      acc = __builtin_amdgcn_mfma_f32_16x16x32_bf16(a, bl, acc, 0, 0, 0);
      acc = __builtin_amdgcn_mfma_f32_16x16x32_bf16(a, bh2, acc, 0, 0, 0);
    }
    #pragma unroll
    for (int rr = 0; rr < 4; rr++){
      int i = ti*16 + quad*4 + rr, p = pb*16 + l16;
      long yb = (long)(b*L_SEQ + l0 + i)*DINNER + h*64 + p;
      y[yb] = fmaf(el[i], acc[rr], y[yb]);
    }
  }
}

__global__ __launch_bounds__(256) void k_gated_rms(
    const float* __restrict__ y, const float* __restrict__ zx, const float* __restrict__ rw,
    unsigned short* __restrict__ ybf)
{
  int r = blockIdx.x, t = threadIdx.x;
  float g[4]; float ss = 0.f;
  #pragma unroll
  for (int i = 0; i < 4; i++){
    int c = t + i*256;
    float z  = zx[(long)r*DINPROJ + c];
    float yv = y[(long)r*DINNER + c];
    g[i] = yv * silu(z);
    ss = fmaf(g[i], g[i], ss);
  }
  #pragma unroll
  for (int o = 1; o < 64; o <<= 1) ss += __shfl_xor(ss, o);
  __shared__ float red[4];
  int w = t >> 6, lane = t & 63;
  if (lane == 0) red[w] = ss;
  __syncthreads();
  float tot = red[0] + red[1] + red[2] + red[3];
  float sc = rsqrtf(tot / (float)DINNER + 1e-5f);
  #pragma unroll
  for (int i = 0; i < 4; i++){
    int c = t + i*256;
    ybf[(long)r*DINNER + c] = f2b(g[i] * sc * rw[c]);
  }
}

__global__ __launch_bounds__(256) void k_add_ln(
    float* __restrict__ x, const float* __restrict__ o,
    const float* __restrict__ lw, const float* __restrict__ lb,
    unsigned short* __restrict__ xbf)
{
  int r = blockIdx.x, t = threadIdx.x;
  float v[2]; float sm = 0.f;
  #pragma unroll
  for (int i = 0; i < 2; i++){ int c = t + i*256; v[i] = x[(long)r*DMODEL + c] + o[(long)r*DMODEL + c]; sm += v[i]; }
  #pragma unroll
  for (int off = 1; off < 64; off <<= 1) sm += __shfl_xor(sm, off);
  __shared__ float red[4]; __shared__ float red2[4];
  int w = t >> 6, lane = t & 63;
  if (lane == 0) red[w] = sm;
  __syncthreads();
  float mu = (red[0] + red[1] + red[2] + red[3]) / (float)DMODEL;
  float var = 0.f;
  #pragma unroll
  for (int i = 0; i < 2; i++){ v[i] -= mu; var = fmaf(v[i], v[i], var); }
  #pragma unroll
  for (int off = 1; off < 64; off <<= 1) var += __shfl_xor(var, off);
  if (lane == 0) red2[w] = var;
  __syncthreads();
  float vv = (red2[0] + red2[1] + red2[2] + red2[3]) / (float)DMODEL;
  float sc = rsqrtf(vv + 1e-5f);
  #pragma unroll
  for (int i = 0; i < 2; i++){
    int c = t + i*256;
    float ov = v[i]*sc*lw[c] + lb[c];
    x[(long)r*DMODEL + c] = ov;
    xbf[(long)r*DMODEL + c] = f2b(ov);
  }
}

extern "C" void kernel_launch(void* const* d_in, const int* in_sizes, int n_in,
                              void* d_out, int out_size, void* d_ws, size_t ws_size,
                              hipStream_t stream)
{
  const int* tokens = (const int*)d_in[0];
  const void* emb = d_in[1];
  int* flag = (int*)d_ws;
  float* ws = (float*)((char*)d_ws + 256);

  ConvArgs ca;
  const int sizes[9] = {10240, 2560, 32, 32, 32, 2048, 1024, 1024, 1000};
  const int idxs[9]  = {3, 4, 5, 6, 7, 8, 10, 11, 13};
  int off = 0;
  for (int s = 0; s < 9; s++){ ca.src[s] = d_in[idxs[s]]; ca.off[s] = off; off += sizes[s]; }
  ca.off[9] = off;

  float* X  = ws + O_X;
  float* ZX = ws + O_ZX;
  float* DT = ws + O_DT;
  float* Y  = ws + O_Y;
  float* Ob = ws + O_O;
  float* LA = ws + O_LA;
  float* Sb = ws + O_S;
  unsigned short* xcb = (unsigned short*)(ws + O_XC);
  unsigned short* ub  = (unsigned short*)(ws + O_UB);
  unsigned short* WiB = ub + U_WI;
  unsigned short* WoB = ub + U_WO;
  unsigned short* WhB = ub + U_WH;
  unsigned short* Xbf = ub + U_XBF;
  unsigned short* Ybf = ub + U_YBF;

  k_prep<<<71 + NPREPW + NROWS, 256, 0, stream>>>(
      ca, d_in[2], d_in[9], d_in[12], tokens, emb, flag,
      ws, WiB, WoB, WhB, X, Xbf);

  for (int layer = 0; layer < 2; layer++){
    k_mfma_nt<<<dim3(WI_PAD/64, NROWS/64), 256, 0, stream>>>(
        Xbf, WiB + (long)layer*WI_PAD*DMODEL, (void*)ZX,
        NROWS, DINPROJ, DMODEL, (const float*)nullptr, flag, 0);
    k_conv_dt<<<NROWS, 256, 0, stream>>>(
        ZX, ws + W_CONVW + layer*5120, ws + W_CONVB + layer*1280, ws + W_DTB + layer*16, xcb, DT);
    k_chunk1<<<dim3(NCH, NHEADSM, BATCH), 256, 0, stream>>>(
        xcb, DT, ws + W_ALOG + layer*16, ws + W_DD + layer*16, Sb, LA, Y);
    k_chunk2<<<1024, 256, 0, stream>>>(Sb, LA);
    k_chunk3<<<dim3(NCH, NHEADSM, BATCH), 256, 0, stream>>>(xcb, Sb, LA, Y);
    k_gated_rms<<<NROWS, 256, 0, stream>>>(Y, ZX, ws + W_RMSW + layer*1024, Ybf);
    k_mfma_nt<<<dim3(DMODEL/64, NROWS/64), 256, 0, stream>>>(
        Ybf, WoB + (long)layer*DMODEL*DINNER, (void*)Ob,
        NROWS, DMODEL, DINNER, (const float*)nullptr, flag, 0);
    k_add_ln<<<NROWS, 256, 0, stream>>>(X, Ob, ws + W_LNW + layer*512, ws + W_LNB + layer*512, Xbf);
  }

  k_mfma_nt<<<dim3(WH_PAD/64, NROWS/64), 256, 0, stream>>>(
      Xbf, WhB, d_out, NROWS, 1000, DMODEL, ws + W_HEADB, flag, 1);
}

// Round 9
// 258.066 us; speedup vs baseline: 1.8595x; 1.0119x over previous
//
#include <hip/hip_runtime.h>

#define L_SEQ 512
#define BATCH 2
#define NROWS (BATCH*L_SEQ)   // 1024
#define DMODEL 512
#define DINNER 1024
#define DSTATE 128
#define NHEADSM 16
#define CONVD 1280
#define DINPROJ 2320
#define QCH 32
#define NCH 16
#define WI_PAD 2368           // 2320 padded to x64
#define WH_PAD 1024           // 1000 padded to x64

// ws float offsets (after 256B header holding the dtype flag)
#define W_CONVW 0
#define W_CONVB 10240
#define W_DTB   12800
#define W_ALOG  12832
#define W_DD    12864
#define W_RMSW  12896
#define W_LNW   14944
#define W_LNB   15968
#define W_HEADB 16992
#define O_X     18048
#define O_ZX    (O_X  + NROWS*DMODEL)    // bf16 ZX (ushort) lives here
#define O_XC    (O_ZX + NROWS*DINPROJ)   // bf16 XC (xcb)
#define O_DT    (O_XC + NROWS*CONVD)
#define O_Y     (O_DT + NROWS*NHEADSM)
#define O_O     (O_Y  + NROWS*DINNER)
#define O_LA    (O_O  + NROWS*DMODEL)
#define O_S     (O_LA + 16384)
#define O_UB    (O_S  + 4194304)
// ushort offsets within bf16 region:
#define U_WI   0
#define U_WO   2424832
#define U_WH   3473408
#define U_XBF  3997696
#define U_YBF  4521984

#define NPREPW (2*WI_PAD + 2*DMODEL + WH_PAD)   // 6848 weight rows

typedef __attribute__((ext_vector_type(8))) short short8;
typedef __attribute__((ext_vector_type(4))) float floatx4;

__device__ __forceinline__ float b2f(unsigned short h){ return __uint_as_float(((unsigned)h)<<16); }
__device__ __forceinline__ unsigned short f2b(float x){
  unsigned u = __float_as_uint(x);
  return (unsigned short)((u + 0x7fffu + ((u>>16)&1u)) >> 16);
}
__device__ __forceinline__ float loadIn(const void* p, long i, int f){
  return f ? b2f(((const unsigned short*)p)[i]) : ((const float*)p)[i];
}
__device__ __forceinline__ float silu(float s){ return s / (1.f + __expf(-s)); }

struct ConvArgs { const void* src[9]; int off[10]; };

// fused startup: self dtype-detect + small-param convert + weight bf16 prep + embedding
__global__ void k_prep(ConvArgs a, const void* __restrict__ wi, const void* __restrict__ wo,
                       const void* __restrict__ wh, const int* __restrict__ tok,
                       const void* __restrict__ emb, int* __restrict__ flagOut,
                       float* __restrict__ dstSmall,
                       unsigned short* __restrict__ WiB, unsigned short* __restrict__ WoB,
                       unsigned short* __restrict__ WhB,
                       float* __restrict__ x, unsigned short* __restrict__ xbf)
{
  // ---- self-detect: low-16 of f32 words are a plausible bf16 iff data is packed bf16 ----
  __shared__ int sflag;
  int t = threadIdx.x;
  if (t < 64){
    int cnt = 0;
    #pragma unroll 8
    for (int i = 0; i < 64; i++){
      unsigned w0 = ((const unsigned*)emb)[t + 64*i];   // coalesced
      unsigned e = (w0 >> 7) & 0xffu;
      cnt += (e >= 100 && e <= 126) ? 1 : 0;
    }
    #pragma unroll
    for (int o = 1; o < 64; o <<= 1) cnt += __shfl_xor(cnt, o);
    if (t == 0) sflag = (cnt > 2048) ? 1 : 0;
  }
  __syncthreads();
  int f = sflag;
  if (blockIdx.x == 0 && t == 0) *flagOut = f;

  int blk = blockIdx.x;
  if (blk < 71){
    int i = blk*256 + t;
    if (i < a.off[9]){
      int s = 0;
      while (i >= a.off[s+1]) s++;
      dstSmall[i] = loadIn(a.src[s], i - a.off[s], f);
    }
    return;
  }
  blk -= 71;
  if (blk < NPREPW){
    int r = blk;
    const void* src = nullptr; unsigned short* dst; long sb = 0, db; int K; bool zero = false;
    if (r < 2*WI_PAD){
      int layer = r / WI_PAD, row = r % WI_PAD;
      K = DMODEL; dst = WiB; db = ((long)layer*WI_PAD + row)*DMODEL;
      if (row < DINPROJ){ src = wi; sb = ((long)layer*DINPROJ + row)*DMODEL; } else zero = true;
    } else if (r < 2*WI_PAD + 2*DMODEL){
      int rr = r - 2*WI_PAD;
      K = DINNER; dst = WoB; db = (long)rr*DINNER;
      src = wo; sb = db;
    } else {
      int row = r - 2*WI_PAD - 2*DMODEL;
      K = DMODEL; dst = WhB; db = (long)row*DMODEL;
      if (row < 1000){ src = wh; sb = db; } else zero = true;
    }
    for (int c = t; c < K; c += 256)
      dst[db + c] = zero ? (unsigned short)0
                         : (f ? ((const unsigned short*)src)[sb + c] : f2b(((const float*)src)[sb + c]));
    return;
  }
  int r = blk - NPREPW;   // embed row
  long base = (long)tok[r] * DMODEL;
  for (int c = t; c < DMODEL; c += 256){
    float v = loadIn(emb, base + c, f);
    x[(long)r*DMODEL + c] = v;
    xbf[(long)r*DMODEL + c] = f ? ((const unsigned short*)emb)[base + c] : f2b(v);
  }
}

// ======== bf16 MFMA GEMM: C[M,N] = A[M,K] @ B[N,K]^T (+bias) ========
// Double-buffered LDS + register prefetch: 1 barrier per K-step, global latency
// hidden behind MFMA. outMode: 0=fp32, 1=dual (bf16 if flag else fp32), 2=bf16 always.
__global__ __launch_bounds__(256) void k_mfma_nt(
    const unsigned short* __restrict__ A, const unsigned short* __restrict__ B,
    void* __restrict__ C, int M, int N, int K,
    const float* __restrict__ bias, const int* __restrict__ flag, int outMode)
{
  __shared__ unsigned short As[2][4096];
  __shared__ unsigned short Bs[2][4096];
  int t = threadIdx.x;
  int w = t >> 6, lane = t & 63;
  int quad = lane >> 4, l16 = lane & 15;
  int m0 = blockIdx.y << 6, n0 = blockIdx.x << 6;
  int wm = (w & 1) << 5, wn = (w >> 1) << 5;
  floatx4 acc[2][2];
  #pragma unroll
  for (int mi = 0; mi < 2; mi++)
    #pragma unroll
    for (int ni = 0; ni < 2; ni++) acc[mi][ni] = (floatx4){0.f,0.f,0.f,0.f};

  int idx0 = (w << 7) + lane;
  int r0s = idx0 >> 3, g0 = idx0 & 7;
  int idx1 = idx0 + 64;
  int r1s = idx1 >> 3, g1 = idx1 & 7;
  long aOff0 = (long)(m0 + r0s)*K + g0*8;
  long aOff1 = (long)(m0 + r1s)*K + g1*8;
  long bOff0 = (long)(n0 + r0s)*K + g0*8;
  long bOff1 = (long)(n0 + r1s)*K + g1*8;
  int w0 = r0s*64 + (g0 ^ (r0s & 7))*8;
  int w1 = r1s*64 + (g1 ^ (r1s & 7))*8;

  // prologue: stage tile 0
  {
    short8 a0 = *(const short8*)&A[aOff0];
    short8 a1 = *(const short8*)&A[aOff1];
    short8 b0 = *(const short8*)&B[bOff0];
    short8 b1 = *(const short8*)&B[bOff1];
    *(short8*)&As[0][w0] = a0; *(short8*)&As[0][w1] = a1;
    *(short8*)&Bs[0][w0] = b0; *(short8*)&Bs[0][w1] = b1;
  }
  __syncthreads();

  int nIt = K >> 6;
  for (int it = 0; it < nIt; it++){
    int cur = it & 1, nxt = cur ^ 1;
    bool more = (it + 1 < nIt);
    short8 na0, na1, nb0, nb1;
    if (more){
      int k0 = (it + 1) << 6;
      na0 = *(const short8*)&A[aOff0 + k0];
      na1 = *(const short8*)&A[aOff1 + k0];
      nb0 = *(const short8*)&B[bOff0 + k0];
      nb1 = *(const short8*)&B[bOff1 + k0];
    }
    #pragma unroll
    for (int ks = 0; ks < 2; ks++){
      short8 af[2], bfr[2];
      #pragma unroll
      for (int mi = 0; mi < 2; mi++){
        int r = wm + mi*16 + l16;
        int pos = ((ks << 2) + quad) ^ (r & 7);
        af[mi] = *(const short8*)&As[cur][r*64 + pos*8];
      }
      #pragma unroll
      for (int ni = 0; ni < 2; ni++){
        int r = wn + ni*16 + l16;
        int pos = ((ks << 2) + quad) ^ (r & 7);
        bfr[ni] = *(const short8*)&Bs[cur][r*64 + pos*8];
      }
      #pragma unroll
      for (int mi = 0; mi < 2; mi++)
        #pragma unroll
        for (int ni = 0; ni < 2; ni++)
          acc[mi][ni] = __builtin_amdgcn_mfma_f32_16x16x32_bf16(af[mi], bfr[ni], acc[mi][ni], 0, 0, 0);
    }
    if (more){
      *(short8*)&As[nxt][w0] = na0; *(short8*)&As[nxt][w1] = na1;
      *(short8*)&Bs[nxt][w0] = nb0; *(short8*)&Bs[nxt][w1] = nb1;
    }
    __syncthreads();
  }

  int f = (outMode == 1) ? *flag : 0;
  #pragma unroll
  for (int mi = 0; mi < 2; mi++)
    #pragma unroll
    for (int ni = 0; ni < 2; ni++){
      int col = n0 + wn + ni*16 + l16;
      if (col >= N) continue;
      float bv = bias ? bias[col] : 0.f;
      #pragma unroll
      for (int rr = 0; rr < 4; rr++){
        int row = m0 + wm + mi*16 + (quad << 2) + rr;
        float v = acc[mi][ni][rr] + bv;
        long idx = (long)row*N + col;
        if (outMode == 2 || (outMode == 1 && f)) ((unsigned short*)C)[idx] = f2b(v);
        else                                     ((float*)C)[idx] = v;
      }
    }
}

// conv + SiLU -> bf16 XC (xcb); dt softplus -> fp32 DT.  ZX is bf16.
__global__ __launch_bounds__(256) void k_conv_dt(
    const unsigned short* __restrict__ zxb, const float* __restrict__ cw, const float* __restrict__ cb,
    const float* __restrict__ dtb, unsigned short* __restrict__ xcb, float* __restrict__ dt)
{
  int r = blockIdx.x; int b = r >> 9, l = r & 511;
  int t = threadIdx.x;
  for (int c = t; c < CONVD; c += 256){
    float s = cb[c];
    #pragma unroll
    for (int k = 0; k < 4; k++){
      int pos = l - 3 + k;
      if (pos >= 0)
        s = fmaf(b2f(zxb[(long)(b*L_SEQ + pos)*DINPROJ + DINNER + c]), cw[c*4 + k], s);
    }
    xcb[(long)r*CONVD + c] = f2b(silu(s));
  }
  if (t < NHEADSM){
    float v = b2f(zxb[(long)r*DINPROJ + DINNER + CONVD + t]) + dtb[t];
    dt[r*NHEADSM + t] = (v > 20.f) ? v : log1pf(__expf(v));  // softplus
  }
}

// ================= chunked SSD scan (MFMA, bf16 staging from xcb) =================
__global__ __launch_bounds__(256) void k_chunk1(
    const unsigned short* __restrict__ xcb, const float* __restrict__ dtbuf,
    const float* __restrict__ alog, const float* __restrict__ dvec,
    float* __restrict__ S, float* __restrict__ LAb, float* __restrict__ y)
{
  int c = blockIdx.x, h = blockIdx.y, b = blockIdx.z;
  int t = threadIdx.x, w = t >> 6, lane = t & 63;
  int quad = lane >> 4, l16 = lane & 15;
  int l0 = c*QCH;
  __shared__ unsigned short XT[64*40];    // XT[p][j] = X[j][p]
  __shared__ unsigned short BTc[128*40];  // BTc[n][j] = coef[j]*B[j][n]
  __shared__ unsigned short Bb[32*136];   // B[j][n]
  __shared__ unsigned short Cb[32*136];   // C[j][n]
  __shared__ unsigned short Gb[32*40];    // G[i][j]
  __shared__ float dtl[32], lal[32], coef[32];
  float A  = -__expf(alog[h]);
  float Dv = dvec[h];

  unsigned short xus[8];
  #pragma unroll
  for (int k = 0; k < 8; k++){
    int idx = t + k*256; int j = idx >> 6, p = idx & 63;
    xus[k] = xcb[(long)(b*L_SEQ + l0 + j)*CONVD + h*64 + p];
  }
  unsigned short bus[16], cus[16];
  #pragma unroll
  for (int k = 0; k < 16; k++){
    int idx = t + k*256; int j = idx >> 7, n = idx & 127;
    long rb = (long)(b*L_SEQ + l0 + j)*CONVD + DINNER;
    bus[k] = xcb[rb + n];
    cus[k] = xcb[rb + DSTATE + n];
  }
  if (t < 32) dtl[t] = dtbuf[(b*L_SEQ + l0 + t)*NHEADSM + h];
  __syncthreads();
  if (t == 0){ float s = 0.f; for (int i = 0; i < 32; i++){ s += dtl[i]; lal[i] = s*A; } }
  __syncthreads();
  if (t < 32){
    coef[t] = __expf(lal[31] - lal[t]) * dtl[t];
    LAb[(b*NHEADSM + h)*L_SEQ + l0 + t] = lal[t];
  }
  __syncthreads();
  #pragma unroll
  for (int k = 0; k < 8; k++){
    int idx = t + k*256; int j = idx >> 6, p = idx & 63;
    XT[p*40 + j] = xus[k];
  }
  #pragma unroll
  for (int k = 0; k < 16; k++){
    int idx = t + k*256; int j = idx >> 7, n = idx & 127;
    Bb[j*136 + n] = bus[k];
    Cb[j*136 + n] = cus[k];
    BTc[n*40 + j] = f2b(b2f(bus[k]) * coef[j]);
  }
  __syncthreads();

  // ---- S: wave w owns p-block w; 8 n-blocks ----
  short8 afS = *(const short8*)&XT[(w*16 + l16)*40 + quad*8];
  floatx4 accS[8];
  #pragma unroll
  for (int nb = 0; nb < 8; nb++){
    short8 bfS = *(const short8*)&BTc[(nb*16 + l16)*40 + quad*8];
    accS[nb] = __builtin_amdgcn_mfma_f32_16x16x32_bf16(afS, bfS, (floatx4){0.f,0.f,0.f,0.f}, 0, 0, 0);
  }
  // ---- G: wave w -> (ti = w&1, tj = w>>1) ----
  int ti = w & 1, tj = w >> 1;
  floatx4 accG = (floatx4){0.f,0.f,0.f,0.f};
  #pragma unroll
  for (int ks = 0; ks < 4; ks++){
    short8 ga = *(const short8*)&Cb[(ti*16 + l16)*136 + ks*32 + quad*8];
    short8 gb = *(const short8*)&Bb[(tj*16 + l16)*136 + ks*32 + quad*8];
    accG = __builtin_amdgcn_mfma_f32_16x16x32_bf16(ga, gb, accG, 0, 0, 0);
  }
  long sb = ((long)((b*NHEADSM + h)*NCH + c))*8192;
  #pragma unroll
  for (int nb = 0; nb < 8; nb++)
    #pragma unroll
    for (int rr = 0; rr < 4; rr++)
      S[sb + (w*16 + quad*4 + rr)*128 + nb*16 + l16] = accS[nb][rr];
  #pragma unroll
  for (int rr = 0; rr < 4; rr++){
    int i = ti*16 + quad*4 + rr, j = tj*16 + l16;
    float g = (j <= i) ? __expf(lal[i] - lal[j]) * dtl[j] * accG[rr] : 0.f;
    Gb[i*40 + j] = f2b(g);
  }
  __syncthreads();
  // ---- Y: wave w -> (ti = w&1, pb = (w>>1)*2 + s) ----
  short8 ag = *(const short8*)&Gb[(ti*16 + l16)*40 + quad*8];
  #pragma unroll
  for (int s = 0; s < 2; s++){
    int pb = (w >> 1)*2 + s;
    short8 bx = *(const short8*)&XT[(pb*16 + l16)*40 + quad*8];
    floatx4 accY = __builtin_amdgcn_mfma_f32_16x16x32_bf16(ag, bx, (floatx4){0.f,0.f,0.f,0.f}, 0, 0, 0);
    #pragma unroll
    for (int rr = 0; rr < 4; rr++){
      int i = ti*16 + quad*4 + rr, p = pb*16 + l16;
      float xval = b2f(XT[p*40 + i]);
      y[(long)(b*L_SEQ + l0 + i)*DINNER + h*64 + p] = fmaf(Dv, xval, accY[rr]);
    }
  }
}

// chunk2: state propagation, IN-PLACE, one thread per state element (1024 blocks).
__global__ __launch_bounds__(256) void k_chunk2(
    float* __restrict__ S, const float* __restrict__ LAb)
{
  int bh = blockIdx.x >> 5;
  int e = ((blockIdx.x & 31) << 8) + threadIdx.x;
  long base = (long)bh*NCH*8192 + e;
  int laBase = bh*L_SEQ;
  float lam[NCH];
  #pragma unroll
  for (int c = 0; c < NCH; c++) lam[c] = __expf(LAb[laBase + c*QCH + QCH - 1]);
  float hr = 0.f;
  #pragma unroll
  for (int c = 0; c < NCH; c++){
    long off = base + (long)c*8192;
    float sv = S[off];
    S[off] = hr;
    hr = fmaf(hr, lam[c], sv);
  }
}

// chunk3: Y += exp(la_i) * C.H^T  [32x64, K=128] via MFMA; C from bf16 xcb, H double-bf16.
__global__ __launch_bounds__(256) void k_chunk3(
    const unsigned short* __restrict__ xcb, const float* __restrict__ H,
    const float* __restrict__ LAb, float* __restrict__ y)
{
  int c = blockIdx.x, h = blockIdx.y, b = blockIdx.z;
  int t = threadIdx.x, w = t >> 6, lane = t & 63;
  int quad = lane >> 4, l16 = lane & 15;
  int l0 = c*QCH, bh = b*NHEADSM + h;
  __shared__ unsigned short Cb[32*136];
  __shared__ unsigned short Hhi[64*136];
  __shared__ unsigned short Hlo[64*136];
  __shared__ float el[32];
  if (t < 32) el[t] = __expf(LAb[bh*L_SEQ + l0 + t]);
  #pragma unroll
  for (int k = 0; k < 16; k++){
    int idx = t + k*256; int j = idx >> 7, n = idx & 127;
    Cb[j*136 + n] = xcb[(long)(b*L_SEQ + l0 + j)*CONVD + DINNER + DSTATE + n];
  }
  long hb = ((long)(bh*NCH + c))*8192;
  #pragma unroll
  for (int k = 0; k < 32; k++){
    int idx = t + k*256; int p = idx >> 7, n = idx & 127;
    float v = H[hb + idx];
    unsigned short hi = f2b(v);
    Hhi[p*136 + n] = hi;
    Hlo[p*136 + n] = f2b(v - b2f(hi));
  }
  __syncthreads();
  int ti = w & 1;
  #pragma unroll
  for (int s = 0; s < 2; s++){
    int pb = (w >> 1)*2 + s;
    floatx4 acc = (floatx4){0.f,0.f,0.f,0.f};
    #pragma unroll
    for (int ks = 0; ks < 4; ks++){
      short8 a  = *(const short8*)&Cb [(ti*16 + l16)*136 + ks*32 + quad*8];
      short8 bl = *(const short8*)&Hlo[(pb*16 + l16)*136 + ks*32 + quad*8];
      short8 bh2= *(const short8*)&Hhi[(pb*16 + l16)*136 + ks*32 + quad*8];
      acc = __builtin_amdgcn_mfma_f32_16x16x32_bf16(a, bl, acc, 0, 0, 0);
      acc = __builtin_amdgcn_mfma_f32_16x16x32_bf16(a, bh2, acc, 0, 0, 0);
    }
    #pragma unroll
    for (int rr = 0; rr < 4; rr++){
      int i = ti*16 + quad*4 + rr, p = pb*16 + l16;
      long yb = (long)(b*L_SEQ + l0 + i)*DINNER + h*64 + p;
      y[yb] = fmaf(el[i], acc[rr], y[yb]);
    }
  }
}

__global__ __launch_bounds__(256) void k_gated_rms(
    const float* __restrict__ y, const unsigned short* __restrict__ zxb, const float* __restrict__ rw,
    unsigned short* __restrict__ ybf)
{
  int r = blockIdx.x, t = threadIdx.x;
  float g[4]; float ss = 0.f;
  #pragma unroll
  for (int i = 0; i < 4; i++){
    int c = t + i*256;
    float z  = b2f(zxb[(long)r*DINPROJ + c]);
    float yv = y[(long)r*DINNER + c];
    g[i] = yv * silu(z);
    ss = fmaf(g[i], g[i], ss);
  }
  #pragma unroll
  for (int o = 1; o < 64; o <<= 1) ss += __shfl_xor(ss, o);
  __shared__ float red[4];
  int w = t >> 6, lane = t & 63;
  if (lane == 0) red[w] = ss;
  __syncthreads();
  float tot = red[0] + red[1] + red[2] + red[3];
  float sc = rsqrtf(tot / (float)DINNER + 1e-5f);
  #pragma unroll
  for (int i = 0; i < 4; i++){
    int c = t + i*256;
    ybf[(long)r*DINNER + c] = f2b(g[i] * sc * rw[c]);
  }
}

__global__ __launch_bounds__(256) void k_add_ln(
    float* __restrict__ x, const float* __restrict__ o,
    const float* __restrict__ lw, const float* __restrict__ lb,
    unsigned short* __restrict__ xbf)
{
  int r = blockIdx.x, t = threadIdx.x;
  float v[2]; float sm = 0.f;
  #pragma unroll
  for (int i = 0; i < 2; i++){ int c = t + i*256; v[i] = x[(long)r*DMODEL + c] + o[(long)r*DMODEL + c]; sm += v[i]; }
  #pragma unroll
  for (int off = 1; off < 64; off <<= 1) sm += __shfl_xor(sm, off);
  __shared__ float red[4]; __shared__ float red2[4];
  int w = t >> 6, lane = t & 63;
  if (lane == 0) red[w] = sm;
  __syncthreads();
  float mu = (red[0] + red[1] + red[2] + red[3]) / (float)DMODEL;
  float var = 0.f;
  #pragma unroll
  for (int i = 0; i < 2; i++){ v[i] -= mu; var = fmaf(v[i], v[i], var); }
  #pragma unroll
  for (int off = 1; off < 64; off <<= 1) var += __shfl_xor(var, off);
  if (lane == 0) red2[w] = var;
  __syncthreads();
  float vv = (red2[0] + red2[1] + red2[2] + red2[3]) / (float)DMODEL;
  float sc = rsqrtf(vv + 1e-5f);
  #pragma unroll
  for (int i = 0; i < 2; i++){
    int c = t + i*256;
    float ov = v[i]*sc*lw[c] + lb[c];
    x[(long)r*DMODEL + c] = ov;
    xbf[(long)r*DMODEL + c] = f2b(ov);
  }
}

extern "C" void kernel_launch(void* const* d_in, const int* in_sizes, int n_in,
                              void* d_out, int out_size, void* d_ws, size_t ws_size,
                              hipStream_t stream)
{
  const int* tokens = (const int*)d_in[0];
  const void* emb = d_in[1];
  int* flag = (int*)d_ws;
  float* ws = (float*)((char*)d_ws + 256);

  ConvArgs ca;
  const int sizes[9] = {10240, 2560, 32, 32, 32, 2048, 1024, 1024, 1000};
  const int idxs[9]  = {3, 4, 5, 6, 7, 8, 10, 11, 13};
  int off = 0;
  for (int s = 0; s < 9; s++){ ca.src[s] = d_in[idxs[s]]; ca.off[s] = off; off += sizes[s]; }
  ca.off[9] = off;

  float* X  = ws + O_X;
  float* DT = ws + O_DT;
  float* Y  = ws + O_Y;
  float* Ob = ws + O_O;
  float* LA = ws + O_LA;
  float* Sb = ws + O_S;
  unsigned short* ZXb = (unsigned short*)(ws + O_ZX);
  unsigned short* xcb = (unsigned short*)(ws + O_XC);
  unsigned short* ub  = (unsigned short*)(ws + O_UB);
  unsigned short* WiB = ub + U_WI;
  unsigned short* WoB = ub + U_WO;
  unsigned short* WhB = ub + U_WH;
  unsigned short* Xbf = ub + U_XBF;
  unsigned short* Ybf = ub + U_YBF;

  k_prep<<<71 + NPREPW + NROWS, 256, 0, stream>>>(
      ca, d_in[2], d_in[9], d_in[12], tokens, emb, flag,
      ws, WiB, WoB, WhB, X, Xbf);

  for (int layer = 0; layer < 2; layer++){
    k_mfma_nt<<<dim3(WI_PAD/64, NROWS/64), 256, 0, stream>>>(
        Xbf, WiB + (long)layer*WI_PAD*DMODEL, (void*)ZXb,
        NROWS, DINPROJ, DMODEL, (const float*)nullptr, flag, 2);
    k_conv_dt<<<NROWS, 256, 0, stream>>>(
        ZXb, ws + W_CONVW + layer*5120, ws + W_CONVB + layer*1280, ws + W_DTB + layer*16, xcb, DT);
    k_chunk1<<<dim3(NCH, NHEADSM, BATCH), 256, 0, stream>>>(
        xcb, DT, ws + W_ALOG + layer*16, ws + W_DD + layer*16, Sb, LA, Y);
    k_chunk2<<<1024, 256, 0, stream>>>(Sb, LA);
    k_chunk3<<<dim3(NCH, NHEADSM, BATCH), 256, 0, stream>>>(xcb, Sb, LA, Y);
    k_gated_rms<<<NROWS, 256, 0, stream>>>(Y, ZXb, ws + W_RMSW + layer*1024, Ybf);
    k_mfma_nt<<<dim3(DMODEL/64, NROWS/64), 256, 0, stream>>>(
        Ybf, WoB + (long)layer*DMODEL*DINNER, (void*)Ob,
        NROWS, DMODEL, DINNER, (const float*)nullptr, flag, 0);
    k_add_ln<<<NROWS, 256, 0, stream>>>(X, Ob, ws + W_LNW + layer*512, ws + W_LNB + layer*512, Xbf);
  }

  k_mfma_nt<<<dim3(WH_PAD/64, NROWS/64), 256, 0, stream>>>(
      Xbf, WhB, d_out, NROWS, 1000, DMODEL, ws + W_HEADB, flag, 1);
}